// Round 1
// 1001.796 us; speedup vs baseline: 1.0983x; 1.0983x over previous
//
#include <hip/hip_runtime.h>
#include <hip/hip_fp16.h>
#include <math.h>

#define N_NODES 50000
#define N_EDGES 800000
#define MPAD 50048            // 391 * 128, so GEMM needs no M bounds checks
#define KPHYS 1024            // A2 physical row width: [hi(512) | lo(512)]
#define KVIRT 1536            // virtual K: hi*hi + lo*hi + hi*lo
#define NKITER (KVIRT / 32)   // 48
#define SCANB ((N_NODES + 255) / 256)  // 196 scan blocks

// ---------------- bf16 helpers ----------------

__device__ __forceinline__ unsigned short bf16_rn(float f) {
    unsigned u = __float_as_uint(f);
    u += 0x7FFFu + ((u >> 16) & 1u);  // round-to-nearest-even
    return (unsigned short)(u >> 16);
}
__device__ __forceinline__ float bf16_f32(unsigned short h) {
    return __uint_as_float(((unsigned)h) << 16);
}

// ---------------- nontemporal helpers ----------------
// fp32 C (self-loop stream) is write-once/read-once-sequential: keep it out of
// L3 LRU priority so A2 (GEMM) and h16 (gather) stay resident.

typedef __attribute__((ext_vector_type(4))) float f4v;
typedef __attribute__((ext_vector_type(2))) float f2v;

__device__ __forceinline__ float4 ntload4(const float* p) {
    f4v v = __builtin_nontemporal_load((const f4v*)p);
    return make_float4(v[0], v[1], v[2], v[3]);
}
__device__ __forceinline__ float2 ntload2(const float* p) {
    f2v v = __builtin_nontemporal_load((const f2v*)p);
    return make_float2(v[0], v[1]);
}

// ---------------- degree / CSR build ----------------

__global__ void zero_int_kernel(int* __restrict__ p, int n) {
    int i = blockIdx.x * blockDim.x + threadIdx.x;
    if (i < n) p[i] = 0;
}

__global__ void count_deg_kernel(const int* __restrict__ dst, int* __restrict__ deg) {
    int e = blockIdx.x * blockDim.x + threadIdx.x;
    if (e < N_EDGES) atomicAdd(&deg[dst[e]], 1);
}

__global__ void dinv_kernel(const int* __restrict__ deg, float* __restrict__ dinv) {
    int i = blockIdx.x * blockDim.x + threadIdx.x;
    if (i < N_NODES) dinv[i] = rsqrtf((float)deg[i] + 1.0f);  // +1 self-loop
}

// 3-kernel scan replaces the single-block (1-CU serial, ~70us) scan_kernel.
__global__ __launch_bounds__(256) void scan1_kernel(const int* __restrict__ deg,
                                                    int* __restrict__ local_scan,
                                                    int* __restrict__ partials) {
    __shared__ int sm[256];
    int b = blockIdx.x, t = threadIdx.x;
    int i = b * 256 + t;
    int v = (i < N_NODES) ? deg[i] : 0;
    sm[t] = v;
    __syncthreads();
    for (int off = 1; off < 256; off <<= 1) {
        int x = (t >= off) ? sm[t - off] : 0;
        __syncthreads();
        sm[t] += x;
        __syncthreads();
    }
    if (i < N_NODES) local_scan[i] = sm[t];
    if (t == 255) partials[b] = sm[255];
}

__global__ __launch_bounds__(256) void scan2_kernel(int* __restrict__ partials) {
    __shared__ int sm[256];
    int t = threadIdx.x;
    sm[t] = (t < SCANB) ? partials[t] : 0;
    __syncthreads();
    for (int off = 1; off < 256; off <<= 1) {
        int x = (t >= off) ? sm[t - off] : 0;
        __syncthreads();
        sm[t] += x;
        __syncthreads();
    }
    if (t < SCANB) partials[t] = (t == 0) ? 0 : sm[t - 1];  // exclusive
}

__global__ __launch_bounds__(256) void scan3_kernel(const int* __restrict__ deg,
                                                    const int* __restrict__ local_scan,
                                                    const int* __restrict__ partials,
                                                    int* __restrict__ offsets,
                                                    int* __restrict__ cursor) {
    int i = blockIdx.x * 256 + threadIdx.x;
    if (i == 0) offsets[0] = 0;
    if (i < N_NODES) {
        int incl = local_scan[i] + partials[blockIdx.x];
        offsets[i + 1] = incl;
        cursor[i] = incl - deg[i];
    }
}

__global__ void fill_csr_kernel(const int* __restrict__ src, const int* __restrict__ dst,
                                int* __restrict__ cursor, int* __restrict__ csr_src,
                                float* __restrict__ csr_w, const float* __restrict__ dinv) {
    int e = blockIdx.x * blockDim.x + threadIdx.x;
    if (e < N_EDGES) {
        int s = src[e], d = dst[e];
        int p = atomicAdd(&cursor[d], 1);
        csr_src[p] = s;
        csr_w[p] = dinv[s] * dinv[d];
    }
}

// ---------------- split-bf16 MFMA GEMM (+ fp16 mirror output) ----------------
// R7's XOR-swizzled staging (coalesced + conflict-free) + explicit LDS
// double-buffer. fp32 C stores are nontemporal: that stream is read exactly
// once (sequentially) by the aggregate self-term, and the measured 306 MB
// FETCH (vs 104 ideal) was L3 capacity eviction of the shared A row-bands.

typedef __attribute__((ext_vector_type(8))) short bf16x8;
typedef __attribute__((ext_vector_type(4))) float floatx4;

#define GLL16(g, l)                                                                   \
    __builtin_amdgcn_global_load_lds((__attribute__((address_space(1))) const void*)(g), \
                                     (__attribute__((address_space(3))) void*)(l), 16, 0, 0)

__global__ __launch_bounds__(256) void gemm_split_bt(const unsigned short* __restrict__ A2,
                                                     const unsigned short* __restrict__ B2T,
                                                     float* __restrict__ C,
                                                     __half* __restrict__ C16, int N) {
    __shared__ unsigned short As[2][128 * 32];  // double-buffered, swizzled chunks
    __shared__ unsigned short Bs[2][128 * 32];

    const int t = threadIdx.x;
    const int lane = t & 63;
    const int quad = lane >> 4;
    const int l15 = lane & 15;
    const int w = t >> 6;
    const int wm = w & 1, wn = w >> 1;
    const int row0 = blockIdx.y * 128;   // grid transposed: y = row band
    const int col0 = blockIdx.x * 128;   //                  x = col block

    floatx4 acc[4][4];
#pragma unroll
    for (int i = 0; i < 4; i++)
#pragma unroll
        for (int j = 0; j < 4; j++) acc[i][j] = (floatx4){0.f, 0.f, 0.f, 0.f};

    // coalesced staging with XOR-swizzled k-chunk (R7)
    const int sr = t >> 2;
    const int sk = ((t & 3) ^ ((t >> 3) & 3)) * 8;
    const unsigned short* Arow0 = A2 + (size_t)(row0 + sr) * KPHYS + sk;
    const unsigned short* Arow1 = Arow0 + (size_t)64 * KPHYS;
    const unsigned short* Brow0 = B2T + (size_t)(col0 + sr) * KVIRT + sk;
    const unsigned short* Brow1 = Brow0 + (size_t)64 * KVIRT;

    // fragment-read swizzle: chunk column = quad ^ ((l15>>1)&3)
    const int fcol = (quad ^ ((l15 >> 1) & 3)) * 8;

    // prologue: stage tile 0 into buffer 0
    {
        GLL16(Arow0 + 0, As[0] + t * 8);
        GLL16(Arow1 + 0, As[0] + 2048 + t * 8);
        GLL16(Brow0 + 0, Bs[0] + t * 8);
        GLL16(Brow1 + 0, Bs[0] + 2048 + t * 8);
    }

    for (int it = 0; it < NKITER; it++) {
        const int cur = it & 1;
        __syncthreads();  // drains prefetch into cur; all reads of cur^1 done
        if (it + 1 < NKITER) {
            const int kbn = (it + 1) * 32;
            const int kAn = (kbn < KPHYS) ? kbn : kbn - KPHYS;
            const int nxt = cur ^ 1;
            GLL16(Arow0 + kAn, As[nxt] + t * 8);
            GLL16(Arow1 + kAn, As[nxt] + 2048 + t * 8);
            GLL16(Brow0 + kbn, Bs[nxt] + t * 8);
            GLL16(Brow1 + kbn, Bs[nxt] + 2048 + t * 8);
        }

        bf16x8 af[4], bf[4];
#pragma unroll
        for (int mt = 0; mt < 4; mt++)
            af[mt] = *(const bf16x8*)(As[cur] + (wm * 64 + mt * 16 + l15) * 32 + fcol);
#pragma unroll
        for (int nt = 0; nt < 4; nt++)
            bf[nt] = *(const bf16x8*)(Bs[cur] + (wn * 64 + nt * 16 + l15) * 32 + fcol);
#pragma unroll
        for (int mt = 0; mt < 4; mt++)
#pragma unroll
            for (int nt = 0; nt < 4; nt++)
                acc[mt][nt] = __builtin_amdgcn_mfma_f32_16x16x32_bf16(af[mt], bf[nt], acc[mt][nt], 0, 0, 0);
    }

#pragma unroll
    for (int mt = 0; mt < 4; mt++) {
#pragma unroll
        for (int r = 0; r < 4; r++) {
            int row = row0 + wm * 64 + mt * 16 + quad * 4 + r;
            float* Cp = C + (size_t)row * N + col0 + wn * 64 + l15;
            __half* Cp16 = C16 + (size_t)row * N + col0 + wn * 64 + l15;
#pragma unroll
            for (int nt = 0; nt < 4; nt++) {
                __builtin_nontemporal_store(acc[mt][nt][r], Cp + nt * 16);  // fp32: streamed, no reuse
                Cp16[nt * 16] = __float2half(acc[mt][nt][r]);               // fp16: gathered next, keep cached
            }
        }
    }
}

// ---------------- weight split (W [K x N] fp32 -> B2T [N x KVIRT] bf16) ----------------

__global__ void wsplit_kernel(const float* __restrict__ W, unsigned short* __restrict__ B2T, int N) {
    int idx = blockIdx.x * blockDim.x + threadIdx.x;
    if (idx >= 512 * N) return;
    int k = idx / N, n = idx % N;
    float v = W[(size_t)k * N + n];
    unsigned short hi = bf16_rn(v);
    unsigned short lo = bf16_rn(v - bf16_f32(hi));
    unsigned short* row = B2T + (size_t)n * KVIRT;
    row[k] = hi;
    row[512 + k] = hi;
    row[1024 + k] = lo;
}

// ---------------- x split (fp32 [N_NODES x 512] -> A2 [MPAD x KPHYS]) ----------------

__global__ __launch_bounds__(256) void split_x_kernel(const float* __restrict__ x,
                                                      unsigned short* __restrict__ A2) {
    int m = blockIdx.x;
    int ch = threadIdx.x * 2;
    unsigned short* arow = A2 + (size_t)m * KPHYS;
    float vx = 0.f, vy = 0.f;
    if (m < N_NODES) {
        float2 v = ntload2(x + (size_t)m * 512 + ch);  // x read exactly once
        vx = v.x;
        vy = v.y;
    }
    unsigned short hx = bf16_rn(vx), hy = bf16_rn(vy);
    arow[ch] = hx;
    arow[ch + 1] = hy;
    arow[512 + ch] = bf16_rn(vx - bf16_f32(hx));
    arow[512 + ch + 1] = bf16_rn(vy - bf16_f32(hy));
}

// ---------------- aggregation ----------------

__device__ __forceinline__ float gelu_tanh(float x) {
    float x3 = x * x * x;
    float inner = 0.7978845608028654f * (x + 0.044715f * x3);
    return 0.5f * x * (1.0f + tanhf(inner));
}

// One wave per node: 64 lanes x 8 fp16 ch = 512 ch. 4 nodes per 256-thread block.
__global__ __launch_bounds__(256) void aggregate_split_kernel(
    const float* __restrict__ h32, const __half* __restrict__ h16,
    const int* __restrict__ offsets, const int* __restrict__ csr_src,
    const float* __restrict__ csr_w, const float* __restrict__ dinv,
    const float* __restrict__ bias, unsigned short* __restrict__ A2) {
    int t = threadIdx.x;
    int node = __builtin_amdgcn_readfirstlane(blockIdx.x * 4 + (t >> 6));
    int ch = (t & 63) * 8;
    unsigned short* arow = A2 + (size_t)node * KPHYS;
    if (node >= N_NODES) {  // zero pad rows (16B per store)
        *(uint4*)(arow + ch) = make_uint4(0, 0, 0, 0);
        *(uint4*)(arow + 512 + ch) = make_uint4(0, 0, 0, 0);
        return;
    }
    int p0 = offsets[node], p1 = offsets[node + 1];
    float a[8] = {0.f, 0.f, 0.f, 0.f, 0.f, 0.f, 0.f, 0.f};

    union H8 { float4 f4; __half2 h2[4]; };
    int p = p0;
    int pend4 = p0 + ((p1 - p0) & ~3);
    for (; p < pend4; p += 4) {
        int s0 = csr_src[p], s1 = csr_src[p + 1], s2 = csr_src[p + 2], s3 = csr_src[p + 3];
        float w0 = csr_w[p], w1 = csr_w[p + 1], w2 = csr_w[p + 2], w3 = csr_w[p + 3];
        H8 v0, v1, v2, v3;
        v0.f4 = *(const float4*)(h16 + (size_t)s0 * 512 + ch);
        v1.f4 = *(const float4*)(h16 + (size_t)s1 * 512 + ch);
        v2.f4 = *(const float4*)(h16 + (size_t)s2 * 512 + ch);
        v3.f4 = *(const float4*)(h16 + (size_t)s3 * 512 + ch);
#pragma unroll
        for (int j = 0; j < 4; j++) {
            float2 c0 = __half22float2(v0.h2[j]);
            float2 c1 = __half22float2(v1.h2[j]);
            float2 c2 = __half22float2(v2.h2[j]);
            float2 c3 = __half22float2(v3.h2[j]);
            a[2 * j] += w0 * c0.x + w1 * c1.x + w2 * c2.x + w3 * c3.x;
            a[2 * j + 1] += w0 * c0.y + w1 * c1.y + w2 * c2.y + w3 * c3.y;
        }
    }
    for (; p < p1; p++) {
        int s = csr_src[p];
        float wg = csr_w[p];
        H8 v;
        v.f4 = *(const float4*)(h16 + (size_t)s * 512 + ch);
#pragma unroll
        for (int j = 0; j < 4; j++) {
            float2 c = __half22float2(v.h2[j]);
            a[2 * j] += wg * c.x;
            a[2 * j + 1] += wg * c.y;
        }
    }

    float di = dinv[node];
    float wself = di * di;
    float4 hs0 = ntload4(h32 + (size_t)node * 512 + ch);      // fp32 stream: read once
    float4 hs1 = ntload4(h32 + (size_t)node * 512 + ch + 4);
    float4 bv0 = *(const float4*)(bias + ch);
    float4 bv1 = *(const float4*)(bias + ch + 4);
    float s[8] = {hs0.x, hs0.y, hs0.z, hs0.w, hs1.x, hs1.y, hs1.z, hs1.w};
    float b[8] = {bv0.x, bv0.y, bv0.z, bv0.w, bv1.x, bv1.y, bv1.z, bv1.w};

    unsigned short hi[8], lo[8];
#pragma unroll
    for (int j = 0; j < 8; j++) {
        float v = gelu_tanh(a[j] + wself * s[j] + b[j]);
        hi[j] = bf16_rn(v);
        lo[j] = bf16_rn(v - bf16_f32(hi[j]));
    }
    *(ushort4*)(arow + ch) = make_ushort4(hi[0], hi[1], hi[2], hi[3]);
    *(ushort4*)(arow + ch + 4) = make_ushort4(hi[4], hi[5], hi[6], hi[7]);
    *(ushort4*)(arow + 512 + ch) = make_ushort4(lo[0], lo[1], lo[2], lo[3]);
    *(ushort4*)(arow + 512 + ch + 4) = make_ushort4(lo[4], lo[5], lo[6], lo[7]);
}

// Final agg: 256 ch, one wave per node (64 lanes x 4 fp16 ch), 4 nodes/block.
__global__ __launch_bounds__(256) void aggregate_final_kernel(
    const float* __restrict__ h32, const __half* __restrict__ h16,
    const int* __restrict__ offsets, const int* __restrict__ csr_src,
    const float* __restrict__ csr_w, const float* __restrict__ dinv,
    const float* __restrict__ bias, float* __restrict__ out) {
    int t = threadIdx.x;
    int node = __builtin_amdgcn_readfirstlane(blockIdx.x * 4 + (t >> 6));
    if (node >= N_NODES) return;
    int ch = (t & 63) * 4;
    int p0 = offsets[node], p1 = offsets[node + 1];
    float ax = 0.f, ay = 0.f, az = 0.f, aw = 0.f;

    union H4 { float2 f2; __half2 h2[2]; };
    int p = p0;
    int pend4 = p0 + ((p1 - p0) & ~3);
    for (; p < pend4; p += 4) {
        int s0 = csr_src[p], s1 = csr_src[p + 1], s2 = csr_src[p + 2], s3 = csr_src[p + 3];
        float w0 = csr_w[p], w1 = csr_w[p + 1], w2 = csr_w[p + 2], w3 = csr_w[p + 3];
        H4 v0, v1, v2, v3;
        v0.f2 = *(const float2*)(h16 + (size_t)s0 * 256 + ch);
        v1.f2 = *(const float2*)(h16 + (size_t)s1 * 256 + ch);
        v2.f2 = *(const float2*)(h16 + (size_t)s2 * 256 + ch);
        v3.f2 = *(const float2*)(h16 + (size_t)s3 * 256 + ch);
        float2 c00 = __half22float2(v0.h2[0]), c01 = __half22float2(v0.h2[1]);
        float2 c10 = __half22float2(v1.h2[0]), c11 = __half22float2(v1.h2[1]);
        float2 c20 = __half22float2(v2.h2[0]), c21 = __half22float2(v2.h2[1]);
        float2 c30 = __half22float2(v3.h2[0]), c31 = __half22float2(v3.h2[1]);
        ax += w0 * c00.x + w1 * c10.x + w2 * c20.x + w3 * c30.x;
        ay += w0 * c00.y + w1 * c10.y + w2 * c20.y + w3 * c30.y;
        az += w0 * c01.x + w1 * c11.x + w2 * c21.x + w3 * c31.x;
        aw += w0 * c01.y + w1 * c11.y + w2 * c21.y + w3 * c31.y;
    }
    for (; p < p1; p++) {
        int s = csr_src[p];
        float wg = csr_w[p];
        H4 v;
        v.f2 = *(const float2*)(h16 + (size_t)s * 256 + ch);
        float2 c0 = __half22float2(v.h2[0]), c1 = __half22float2(v.h2[1]);
        ax += wg * c0.x; ay += wg * c0.y; az += wg * c1.x; aw += wg * c1.y;
    }

    float di = dinv[node];
    float wself = di * di;
    float4 hs = ntload4(h32 + (size_t)node * 256 + ch);  // fp32 stream: read once
    float4 bv = *(const float4*)(bias + ch);
    float4 o = make_float4(ax + wself * hs.x + bv.x, ay + wself * hs.y + bv.y,
                           az + wself * hs.z + bv.z, aw + wself * hs.w + bv.w);
    *(float4*)(out + (size_t)node * 256 + ch) = o;
}

// ---------------- launch ----------------

static inline char* align16(char* p) { return (char*)(((size_t)p + 15) & ~(size_t)15); }

extern "C" void kernel_launch(void* const* d_in, const int* in_sizes, int n_in,
                              void* d_out, int out_size, void* d_ws, size_t ws_size,
                              hipStream_t stream) {
    const float* x  = (const float*)d_in[0];
    const int* eidx = (const int*)d_in[1];
    const float* W1 = (const float*)d_in[2];
    const float* b1 = (const float*)d_in[3];
    const float* W2 = (const float*)d_in[4];
    const float* b2 = (const float*)d_in[5];
    const float* W3 = (const float*)d_in[6];
    const float* b3 = (const float*)d_in[7];
    float* out = (float*)d_out;

    const int* src = eidx;
    const int* dst = eidx + N_EDGES;

    char* ws = (char*)d_ws;
    unsigned short* A2 = (unsigned short*)ws;  ws += (size_t)MPAD * KPHYS * 2;   // 102.5 MB
    float* Cbuf = (float*)ws;                  ws += (size_t)MPAD * 512 * 4;      // 102.5 MB
    __half* C16 = (__half*)ws;                 ws += (size_t)MPAD * 512 * 2;      // 51.2 MB
    unsigned short* B2T1 = (unsigned short*)ws; ws += (size_t)512 * KVIRT * 2;
    unsigned short* B2T2 = (unsigned short*)ws; ws += (size_t)512 * KVIRT * 2;
    unsigned short* B2T3 = (unsigned short*)ws; ws += (size_t)256 * KVIRT * 2;
    int* deg = (int*)ws;        ws = align16(ws + (size_t)N_NODES * 4);
    float* dinv = (float*)ws;   ws = align16(ws + (size_t)N_NODES * 4);
    int* offsets = (int*)ws;    ws = align16(ws + (size_t)(N_NODES + 1) * 4);
    int* cursor = (int*)ws;     ws = align16(ws + (size_t)N_NODES * 4);
    int* csr_src = (int*)ws;    ws = align16(ws + (size_t)N_EDGES * 4);
    float* csr_w = (float*)ws;  ws = align16(ws + (size_t)N_EDGES * 4);
    int* local_scan = (int*)ws; ws = align16(ws + (size_t)N_NODES * 4);
    int* partials = (int*)ws;   ws = align16(ws + (size_t)SCANB * 4);

    // ---- CSR build ----
    zero_int_kernel<<<(N_NODES + 255) / 256, 256, 0, stream>>>(deg, N_NODES);
    count_deg_kernel<<<(N_EDGES + 255) / 256, 256, 0, stream>>>(dst, deg);
    dinv_kernel<<<(N_NODES + 255) / 256, 256, 0, stream>>>(deg, dinv);
    scan1_kernel<<<SCANB, 256, 0, stream>>>(deg, local_scan, partials);
    scan2_kernel<<<1, 256, 0, stream>>>(partials);
    scan3_kernel<<<SCANB, 256, 0, stream>>>(deg, local_scan, partials, offsets, cursor);
    fill_csr_kernel<<<(N_EDGES + 255) / 256, 256, 0, stream>>>(src, dst, cursor, csr_src, csr_w, dinv);

    // ---- weight + input splits ----
    wsplit_kernel<<<(512 * 512 + 255) / 256, 256, 0, stream>>>(W1, B2T1, 512);
    wsplit_kernel<<<(512 * 512 + 255) / 256, 256, 0, stream>>>(W2, B2T2, 512);
    wsplit_kernel<<<(512 * 256 + 255) / 256, 256, 0, stream>>>(W3, B2T3, 256);
    split_x_kernel<<<MPAD, 256, 0, stream>>>(x, A2);

    // ---- layer 1 ----
    {
        dim3 grid(512 / 128, MPAD / 128);  // x = col block, y = row band
        gemm_split_bt<<<grid, 256, 0, stream>>>(A2, B2T1, Cbuf, C16, 512);
        aggregate_split_kernel<<<MPAD / 4, 256, 0, stream>>>(Cbuf, C16, offsets, csr_src, csr_w, dinv, b1, A2);
    }
    // ---- layer 2 ----
    {
        dim3 grid(512 / 128, MPAD / 128);
        gemm_split_bt<<<grid, 256, 0, stream>>>(A2, B2T2, Cbuf, C16, 512);
        aggregate_split_kernel<<<MPAD / 4, 256, 0, stream>>>(Cbuf, C16, offsets, csr_src, csr_w, dinv, b2, A2);
    }
    // ---- layer 3 ----
    {
        dim3 grid(256 / 128, MPAD / 128);
        gemm_split_bt<<<grid, 256, 0, stream>>>(A2, B2T3, Cbuf, C16, 256);
        aggregate_final_kernel<<<MPAD / 4, 256, 0, stream>>>(Cbuf, C16, offsets, csr_src, csr_w, dinv, b3, out);
    }
}

// Round 2
// 923.861 us; speedup vs baseline: 1.1910x; 1.0844x over previous
//
#include <hip/hip_runtime.h>
#include <hip/hip_fp16.h>
#include <math.h>

#define N_NODES 50000
#define N_EDGES 800000
#define MPAD 50048            // 391 * 128, so GEMM needs no M bounds checks
#define KPHYS 1024            // A2 physical row width: [hi(512) | lo(512)]
#define KB 1024               // B2T physical row width: [hi(512) | lo(512)]
#define NOUTER 16             // 16 outer iters x 32 cols = 512 K
#define SCANB ((N_NODES + 255) / 256)  // 196 scan blocks

// ---------------- bf16 helpers ----------------

__device__ __forceinline__ unsigned short bf16_rn(float f) {
    unsigned u = __float_as_uint(f);
    u += 0x7FFFu + ((u >> 16) & 1u);  // round-to-nearest-even
    return (unsigned short)(u >> 16);
}
__device__ __forceinline__ float bf16_f32(unsigned short h) {
    return __uint_as_float(((unsigned)h) << 16);
}

// ---------------- nontemporal helpers ----------------

typedef __attribute__((ext_vector_type(4))) float f4v;
typedef __attribute__((ext_vector_type(2))) float f2v;

__device__ __forceinline__ float4 ntload4(const float* p) {
    f4v v = __builtin_nontemporal_load((const f4v*)p);
    return make_float4(v[0], v[1], v[2], v[3]);
}
__device__ __forceinline__ float2 ntload2(const float* p) {
    f2v v = __builtin_nontemporal_load((const f2v*)p);
    return make_float2(v[0], v[1]);
}

// ---------------- degree / CSR build ----------------

__global__ void zero_int_kernel(int* __restrict__ p, int n) {
    int i = blockIdx.x * blockDim.x + threadIdx.x;
    if (i < n) p[i] = 0;
}

__global__ void count_deg_kernel(const int* __restrict__ dst, int* __restrict__ deg) {
    int e = blockIdx.x * blockDim.x + threadIdx.x;
    if (e < N_EDGES) atomicAdd(&deg[dst[e]], 1);
}

__global__ void dinv_kernel(const int* __restrict__ deg, float* __restrict__ dinv) {
    int i = blockIdx.x * blockDim.x + threadIdx.x;
    if (i < N_NODES) dinv[i] = rsqrtf((float)deg[i] + 1.0f);  // +1 self-loop
}

// 3-kernel scan (multi-block; replaced the 1-CU serial scan)
__global__ __launch_bounds__(256) void scan1_kernel(const int* __restrict__ deg,
                                                    int* __restrict__ local_scan,
                                                    int* __restrict__ partials) {
    __shared__ int sm[256];
    int b = blockIdx.x, t = threadIdx.x;
    int i = b * 256 + t;
    int v = (i < N_NODES) ? deg[i] : 0;
    sm[t] = v;
    __syncthreads();
    for (int off = 1; off < 256; off <<= 1) {
        int x = (t >= off) ? sm[t - off] : 0;
        __syncthreads();
        sm[t] += x;
        __syncthreads();
    }
    if (i < N_NODES) local_scan[i] = sm[t];
    if (t == 255) partials[b] = sm[255];
}

__global__ __launch_bounds__(256) void scan2_kernel(int* __restrict__ partials) {
    __shared__ int sm[256];
    int t = threadIdx.x;
    sm[t] = (t < SCANB) ? partials[t] : 0;
    __syncthreads();
    for (int off = 1; off < 256; off <<= 1) {
        int x = (t >= off) ? sm[t - off] : 0;
        __syncthreads();
        sm[t] += x;
        __syncthreads();
    }
    if (t < SCANB) partials[t] = (t == 0) ? 0 : sm[t - 1];  // exclusive
}

__global__ __launch_bounds__(256) void scan3_kernel(const int* __restrict__ deg,
                                                    const int* __restrict__ local_scan,
                                                    const int* __restrict__ partials,
                                                    int* __restrict__ offsets,
                                                    int* __restrict__ cursor) {
    int i = blockIdx.x * 256 + threadIdx.x;
    if (i == 0) offsets[0] = 0;
    if (i < N_NODES) {
        int incl = local_scan[i] + partials[blockIdx.x];
        offsets[i + 1] = incl;
        cursor[i] = incl - deg[i];
    }
}

__global__ void fill_csr_kernel(const int* __restrict__ src, const int* __restrict__ dst,
                                int* __restrict__ cursor, int* __restrict__ csr_src,
                                float* __restrict__ csr_w, const float* __restrict__ dinv) {
    int e = blockIdx.x * blockDim.x + threadIdx.x;
    if (e < N_EDGES) {
        int s = src[e], d = dst[e];
        int p = atomicAdd(&cursor[d], 1);
        csr_src[p] = s;
        csr_w[p] = dinv[s] * dinv[d];
    }
}

// ---------------- split-bf16 MFMA GEMM (+ fp16 mirror output) ----------------
// R1 restructure: one outer iteration stages {A_hi, A_lo, B_hi, B_lo} 32-col
// chunks and runs all three split passes (hi*hi, lo*hi, hi*lo) off that single
// staging. A is staged once (1024 cols) instead of 1.5x (1536), and each
// barrier now covers 48 MFMAs instead of 16 (barrier-drain amortization).

typedef __attribute__((ext_vector_type(8))) short bf16x8;
typedef __attribute__((ext_vector_type(4))) float floatx4;

#define GLL16(g, l)                                                                   \
    __builtin_amdgcn_global_load_lds((__attribute__((address_space(1))) const void*)(g), \
                                     (__attribute__((address_space(3))) void*)(l), 16, 0, 0)

__global__ __launch_bounds__(256) void gemm_split_bt(const unsigned short* __restrict__ A2,
                                                     const unsigned short* __restrict__ B2T,
                                                     float* __restrict__ C,
                                                     __half* __restrict__ C16, int N) {
    // [buf][hi/lo] 128x32 chunks, double-buffered: 64 KiB total
    __shared__ unsigned short As[2][2][128 * 32];
    __shared__ unsigned short Bs[2][2][128 * 32];

    const int t = threadIdx.x;
    const int lane = t & 63;
    const int quad = lane >> 4;
    const int l15 = lane & 15;
    const int w = t >> 6;
    const int wm = w & 1, wn = w >> 1;
    const int row0 = blockIdx.y * 128;   // grid transposed: y = row band
    const int col0 = blockIdx.x * 128;   //                  x = col block

    floatx4 acc[4][4];
#pragma unroll
    for (int i = 0; i < 4; i++)
#pragma unroll
        for (int j = 0; j < 4; j++) acc[i][j] = (floatx4){0.f, 0.f, 0.f, 0.f};

    // coalesced staging with XOR-swizzled k-chunk
    const int sr = t >> 2;
    const int sk = ((t & 3) ^ ((t >> 3) & 3)) * 8;
    const unsigned short* Arow0 = A2 + (size_t)(row0 + sr) * KPHYS + sk;
    const unsigned short* Arow1 = Arow0 + (size_t)64 * KPHYS;
    const unsigned short* Brow0 = B2T + (size_t)(col0 + sr) * KB + sk;
    const unsigned short* Brow1 = Brow0 + (size_t)64 * KB;

    // fragment-read swizzle: chunk column = quad ^ ((l15>>1)&3)
    const int fcol = (quad ^ ((l15 >> 1) & 3)) * 8;

#define STAGE(buf, k32)                                            \
    do {                                                           \
        GLL16(Arow0 + (k32), As[buf][0] + t * 8);                  \
        GLL16(Arow1 + (k32), As[buf][0] + 2048 + t * 8);           \
        GLL16(Arow0 + 512 + (k32), As[buf][1] + t * 8);            \
        GLL16(Arow1 + 512 + (k32), As[buf][1] + 2048 + t * 8);     \
        GLL16(Brow0 + (k32), Bs[buf][0] + t * 8);                  \
        GLL16(Brow1 + (k32), Bs[buf][0] + 2048 + t * 8);           \
        GLL16(Brow0 + 512 + (k32), Bs[buf][1] + t * 8);            \
        GLL16(Brow1 + 512 + (k32), Bs[buf][1] + 2048 + t * 8);     \
    } while (0)

    // prologue: stage chunk 0 into buffer 0
    STAGE(0, 0);

    for (int it = 0; it < NOUTER; it++) {
        const int cur = it & 1;
        __syncthreads();  // drains prefetch into cur; all reads of cur^1 done
        if (it + 1 < NOUTER) STAGE(cur ^ 1, (it + 1) * 32);

        bf16x8 afh[4], afl[4], bfh[4], bfl[4];
#pragma unroll
        for (int mt = 0; mt < 4; mt++) {
            const int ro = (wm * 64 + mt * 16 + l15) * 32 + fcol;
            afh[mt] = *(const bf16x8*)(As[cur][0] + ro);
            afl[mt] = *(const bf16x8*)(As[cur][1] + ro);
        }
#pragma unroll
        for (int nt = 0; nt < 4; nt++) {
            const int ro = (wn * 64 + nt * 16 + l15) * 32 + fcol;
            bfh[nt] = *(const bf16x8*)(Bs[cur][0] + ro);
            bfl[nt] = *(const bf16x8*)(Bs[cur][1] + ro);
        }
        // pass 1: hi*hi
#pragma unroll
        for (int mt = 0; mt < 4; mt++)
#pragma unroll
            for (int nt = 0; nt < 4; nt++)
                acc[mt][nt] = __builtin_amdgcn_mfma_f32_16x16x32_bf16(afh[mt], bfh[nt], acc[mt][nt], 0, 0, 0);
        // pass 2: lo*hi
#pragma unroll
        for (int mt = 0; mt < 4; mt++)
#pragma unroll
            for (int nt = 0; nt < 4; nt++)
                acc[mt][nt] = __builtin_amdgcn_mfma_f32_16x16x32_bf16(afl[mt], bfh[nt], acc[mt][nt], 0, 0, 0);
        // pass 3: hi*lo
#pragma unroll
        for (int mt = 0; mt < 4; mt++)
#pragma unroll
            for (int nt = 0; nt < 4; nt++)
                acc[mt][nt] = __builtin_amdgcn_mfma_f32_16x16x32_bf16(afh[mt], bfl[nt], acc[mt][nt], 0, 0, 0);
    }
#undef STAGE

#pragma unroll
    for (int mt = 0; mt < 4; mt++) {
#pragma unroll
        for (int r = 0; r < 4; r++) {
            int row = row0 + wm * 64 + mt * 16 + quad * 4 + r;
            float* Cp = C + (size_t)row * N + col0 + wn * 64 + l15;
            __half* Cp16 = C16 + (size_t)row * N + col0 + wn * 64 + l15;
#pragma unroll
            for (int nt = 0; nt < 4; nt++) {
                __builtin_nontemporal_store(acc[mt][nt][r], Cp + nt * 16);  // fp32: streamed, no reuse
                Cp16[nt * 16] = __float2half(acc[mt][nt][r]);               // fp16: gathered next
            }
        }
    }
}

// ---------------- weight split (W [K x N] fp32 -> B2T [N x KB] bf16) ----------------

__global__ void wsplit_kernel(const float* __restrict__ W, unsigned short* __restrict__ B2T, int N) {
    int idx = blockIdx.x * blockDim.x + threadIdx.x;
    if (idx >= 512 * N) return;
    int k = idx / N, n = idx % N;
    float v = W[(size_t)k * N + n];
    unsigned short hi = bf16_rn(v);
    unsigned short lo = bf16_rn(v - bf16_f32(hi));
    unsigned short* row = B2T + (size_t)n * KB;
    row[k] = hi;
    row[512 + k] = lo;
}

// ---------------- x split (fp32 [N_NODES x 512] -> A2 [MPAD x KPHYS]) ----------------

__global__ __launch_bounds__(256) void split_x_kernel(const float* __restrict__ x,
                                                      unsigned short* __restrict__ A2) {
    int m = blockIdx.x;
    int ch = threadIdx.x * 2;
    unsigned short* arow = A2 + (size_t)m * KPHYS;
    float vx = 0.f, vy = 0.f;
    if (m < N_NODES) {
        float2 v = ntload2(x + (size_t)m * 512 + ch);  // x read exactly once
        vx = v.x;
        vy = v.y;
    }
    unsigned short hx = bf16_rn(vx), hy = bf16_rn(vy);
    arow[ch] = hx;
    arow[ch + 1] = hy;
    arow[512 + ch] = bf16_rn(vx - bf16_f32(hx));
    arow[512 + ch + 1] = bf16_rn(vy - bf16_f32(hy));
}

// ---------------- aggregation ----------------

__device__ __forceinline__ float gelu_tanh(float x) {
    float x3 = x * x * x;
    float inner = 0.7978845608028654f * (x + 0.044715f * x3);
    return 0.5f * x * (1.0f + tanhf(inner));
}

// One wave per node: 64 lanes x 8 fp16 ch = 512 ch. 4 nodes per 256-thread block.
__global__ __launch_bounds__(256) void aggregate_split_kernel(
    const float* __restrict__ h32, const __half* __restrict__ h16,
    const int* __restrict__ offsets, const int* __restrict__ csr_src,
    const float* __restrict__ csr_w, const float* __restrict__ dinv,
    const float* __restrict__ bias, unsigned short* __restrict__ A2) {
    int t = threadIdx.x;
    int node = __builtin_amdgcn_readfirstlane(blockIdx.x * 4 + (t >> 6));
    int ch = (t & 63) * 8;
    unsigned short* arow = A2 + (size_t)node * KPHYS;
    if (node >= N_NODES) {  // zero pad rows (16B per store)
        *(uint4*)(arow + ch) = make_uint4(0, 0, 0, 0);
        *(uint4*)(arow + 512 + ch) = make_uint4(0, 0, 0, 0);
        return;
    }
    int p0 = offsets[node], p1 = offsets[node + 1];
    float a[8] = {0.f, 0.f, 0.f, 0.f, 0.f, 0.f, 0.f, 0.f};

    union H8 { float4 f4; __half2 h2[4]; };
    int p = p0;
    int pend4 = p0 + ((p1 - p0) & ~3);
    for (; p < pend4; p += 4) {
        int s0 = csr_src[p], s1 = csr_src[p + 1], s2 = csr_src[p + 2], s3 = csr_src[p + 3];
        float w0 = csr_w[p], w1 = csr_w[p + 1], w2 = csr_w[p + 2], w3 = csr_w[p + 3];
        H8 v0, v1, v2, v3;
        v0.f4 = *(const float4*)(h16 + (size_t)s0 * 512 + ch);
        v1.f4 = *(const float4*)(h16 + (size_t)s1 * 512 + ch);
        v2.f4 = *(const float4*)(h16 + (size_t)s2 * 512 + ch);
        v3.f4 = *(const float4*)(h16 + (size_t)s3 * 512 + ch);
#pragma unroll
        for (int j = 0; j < 4; j++) {
            float2 c0 = __half22float2(v0.h2[j]);
            float2 c1 = __half22float2(v1.h2[j]);
            float2 c2 = __half22float2(v2.h2[j]);
            float2 c3 = __half22float2(v3.h2[j]);
            a[2 * j] += w0 * c0.x + w1 * c1.x + w2 * c2.x + w3 * c3.x;
            a[2 * j + 1] += w0 * c0.y + w1 * c1.y + w2 * c2.y + w3 * c3.y;
        }
    }
    for (; p < p1; p++) {
        int s = csr_src[p];
        float wg = csr_w[p];
        H8 v;
        v.f4 = *(const float4*)(h16 + (size_t)s * 512 + ch);
#pragma unroll
        for (int j = 0; j < 4; j++) {
            float2 c = __half22float2(v.h2[j]);
            a[2 * j] += wg * c.x;
            a[2 * j + 1] += wg * c.y;
        }
    }

    float di = dinv[node];
    float wself = di * di;
    float4 hs0 = ntload4(h32 + (size_t)node * 512 + ch);      // fp32 stream: read once
    float4 hs1 = ntload4(h32 + (size_t)node * 512 + ch + 4);
    float4 bv0 = *(const float4*)(bias + ch);
    float4 bv1 = *(const float4*)(bias + ch + 4);
    float s[8] = {hs0.x, hs0.y, hs0.z, hs0.w, hs1.x, hs1.y, hs1.z, hs1.w};
    float b[8] = {bv0.x, bv0.y, bv0.z, bv0.w, bv1.x, bv1.y, bv1.z, bv1.w};

    unsigned short hi[8], lo[8];
#pragma unroll
    for (int j = 0; j < 8; j++) {
        float v = gelu_tanh(a[j] + wself * s[j] + b[j]);
        hi[j] = bf16_rn(v);
        lo[j] = bf16_rn(v - bf16_f32(hi[j]));
    }
    *(ushort4*)(arow + ch) = make_ushort4(hi[0], hi[1], hi[2], hi[3]);
    *(ushort4*)(arow + ch + 4) = make_ushort4(hi[4], hi[5], hi[6], hi[7]);
    *(ushort4*)(arow + 512 + ch) = make_ushort4(lo[0], lo[1], lo[2], lo[3]);
    *(ushort4*)(arow + 512 + ch + 4) = make_ushort4(lo[4], lo[5], lo[6], lo[7]);
}

// Final agg: 256 ch, one wave per node (64 lanes x 4 fp16 ch), 4 nodes/block.
__global__ __launch_bounds__(256) void aggregate_final_kernel(
    const float* __restrict__ h32, const __half* __restrict__ h16,
    const int* __restrict__ offsets, const int* __restrict__ csr_src,
    const float* __restrict__ csr_w, const float* __restrict__ dinv,
    const float* __restrict__ bias, float* __restrict__ out) {
    int t = threadIdx.x;
    int node = __builtin_amdgcn_readfirstlane(blockIdx.x * 4 + (t >> 6));
    if (node >= N_NODES) return;
    int ch = (t & 63) * 4;
    int p0 = offsets[node], p1 = offsets[node + 1];
    float ax = 0.f, ay = 0.f, az = 0.f, aw = 0.f;

    union H4 { float2 f2; __half2 h2[2]; };
    int p = p0;
    int pend4 = p0 + ((p1 - p0) & ~3);
    for (; p < pend4; p += 4) {
        int s0 = csr_src[p], s1 = csr_src[p + 1], s2 = csr_src[p + 2], s3 = csr_src[p + 3];
        float w0 = csr_w[p], w1 = csr_w[p + 1], w2 = csr_w[p + 2], w3 = csr_w[p + 3];
        H4 v0, v1, v2, v3;
        v0.f2 = *(const float2*)(h16 + (size_t)s0 * 256 + ch);
        v1.f2 = *(const float2*)(h16 + (size_t)s1 * 256 + ch);
        v2.f2 = *(const float2*)(h16 + (size_t)s2 * 256 + ch);
        v3.f2 = *(const float2*)(h16 + (size_t)s3 * 256 + ch);
        float2 c00 = __half22float2(v0.h2[0]), c01 = __half22float2(v0.h2[1]);
        float2 c10 = __half22float2(v1.h2[0]), c11 = __half22float2(v1.h2[1]);
        float2 c20 = __half22float2(v2.h2[0]), c21 = __half22float2(v2.h2[1]);
        float2 c30 = __half22float2(v3.h2[0]), c31 = __half22float2(v3.h2[1]);
        ax += w0 * c00.x + w1 * c10.x + w2 * c20.x + w3 * c30.x;
        ay += w0 * c00.y + w1 * c10.y + w2 * c20.y + w3 * c30.y;
        az += w0 * c01.x + w1 * c11.x + w2 * c21.x + w3 * c31.x;
        aw += w0 * c01.y + w1 * c11.y + w2 * c21.y + w3 * c31.y;
    }
    for (; p < p1; p++) {
        int s = csr_src[p];
        float wg = csr_w[p];
        H4 v;
        v.f2 = *(const float2*)(h16 + (size_t)s * 256 + ch);
        float2 c0 = __half22float2(v.h2[0]), c1 = __half22float2(v.h2[1]);
        ax += wg * c0.x; ay += wg * c0.y; az += wg * c1.x; aw += wg * c1.y;
    }

    float di = dinv[node];
    float wself = di * di;
    float4 hs = ntload4(h32 + (size_t)node * 256 + ch);  // fp32 stream: read once
    float4 bv = *(const float4*)(bias + ch);
    float4 o = make_float4(ax + wself * hs.x + bv.x, ay + wself * hs.y + bv.y,
                           az + wself * hs.z + bv.z, aw + wself * hs.w + bv.w);
    *(float4*)(out + (size_t)node * 256 + ch) = o;
}

// ---------------- launch ----------------

static inline char* align16(char* p) { return (char*)(((size_t)p + 15) & ~(size_t)15); }

extern "C" void kernel_launch(void* const* d_in, const int* in_sizes, int n_in,
                              void* d_out, int out_size, void* d_ws, size_t ws_size,
                              hipStream_t stream) {
    const float* x  = (const float*)d_in[0];
    const int* eidx = (const int*)d_in[1];
    const float* W1 = (const float*)d_in[2];
    const float* b1 = (const float*)d_in[3];
    const float* W2 = (const float*)d_in[4];
    const float* b2 = (const float*)d_in[5];
    const float* W3 = (const float*)d_in[6];
    const float* b3 = (const float*)d_in[7];
    float* out = (float*)d_out;

    const int* src = eidx;
    const int* dst = eidx + N_EDGES;

    char* ws = (char*)d_ws;
    unsigned short* A2 = (unsigned short*)ws;  ws += (size_t)MPAD * KPHYS * 2;   // 102.5 MB
    float* Cbuf = (float*)ws;                  ws += (size_t)MPAD * 512 * 4;      // 102.5 MB
    __half* C16 = (__half*)ws;                 ws += (size_t)MPAD * 512 * 2;      // 51.2 MB
    unsigned short* B2T1 = (unsigned short*)ws; ws += (size_t)512 * KB * 2;
    unsigned short* B2T2 = (unsigned short*)ws; ws += (size_t)512 * KB * 2;
    unsigned short* B2T3 = (unsigned short*)ws; ws += (size_t)256 * KB * 2;
    int* deg = (int*)ws;        ws = align16(ws + (size_t)N_NODES * 4);
    float* dinv = (float*)ws;   ws = align16(ws + (size_t)N_NODES * 4);
    int* offsets = (int*)ws;    ws = align16(ws + (size_t)(N_NODES + 1) * 4);
    int* cursor = (int*)ws;     ws = align16(ws + (size_t)N_NODES * 4);
    int* csr_src = (int*)ws;    ws = align16(ws + (size_t)N_EDGES * 4);
    float* csr_w = (float*)ws;  ws = align16(ws + (size_t)N_EDGES * 4);
    int* local_scan = (int*)ws; ws = align16(ws + (size_t)N_NODES * 4);
    int* partials = (int*)ws;   ws = align16(ws + (size_t)SCANB * 4);

    // ---- CSR build ----
    zero_int_kernel<<<(N_NODES + 255) / 256, 256, 0, stream>>>(deg, N_NODES);
    count_deg_kernel<<<(N_EDGES + 255) / 256, 256, 0, stream>>>(dst, deg);
    dinv_kernel<<<(N_NODES + 255) / 256, 256, 0, stream>>>(deg, dinv);
    scan1_kernel<<<SCANB, 256, 0, stream>>>(deg, local_scan, partials);
    scan2_kernel<<<1, 256, 0, stream>>>(partials);
    scan3_kernel<<<SCANB, 256, 0, stream>>>(deg, local_scan, partials, offsets, cursor);
    fill_csr_kernel<<<(N_EDGES + 255) / 256, 256, 0, stream>>>(src, dst, cursor, csr_src, csr_w, dinv);

    // ---- weight + input splits ----
    wsplit_kernel<<<(512 * 512 + 255) / 256, 256, 0, stream>>>(W1, B2T1, 512);
    wsplit_kernel<<<(512 * 512 + 255) / 256, 256, 0, stream>>>(W2, B2T2, 512);
    wsplit_kernel<<<(512 * 256 + 255) / 256, 256, 0, stream>>>(W3, B2T3, 256);
    split_x_kernel<<<MPAD, 256, 0, stream>>>(x, A2);

    // ---- layer 1 ----
    {
        dim3 grid(512 / 128, MPAD / 128);  // x = col block, y = row band
        gemm_split_bt<<<grid, 256, 0, stream>>>(A2, B2T1, Cbuf, C16, 512);
        aggregate_split_kernel<<<MPAD / 4, 256, 0, stream>>>(Cbuf, C16, offsets, csr_src, csr_w, dinv, b1, A2);
    }
    // ---- layer 2 ----
    {
        dim3 grid(512 / 128, MPAD / 128);
        gemm_split_bt<<<grid, 256, 0, stream>>>(A2, B2T2, Cbuf, C16, 512);
        aggregate_split_kernel<<<MPAD / 4, 256, 0, stream>>>(Cbuf, C16, offsets, csr_src, csr_w, dinv, b2, A2);
    }
    // ---- layer 3 ----
    {
        dim3 grid(256 / 128, MPAD / 128);
        gemm_split_bt<<<grid, 256, 0, stream>>>(A2, B2T3, Cbuf, C16, 256);
        aggregate_final_kernel<<<MPAD / 4, 256, 0, stream>>>(Cbuf, C16, offsets, csr_src, csr_w, dinv, b3, out);
    }
}

// Round 3
// 919.827 us; speedup vs baseline: 1.1962x; 1.0044x over previous
//
#include <hip/hip_runtime.h>
#include <hip/hip_fp16.h>
#include <math.h>

#define N_NODES 50000
#define N_EDGES 800000
#define MPAD 50048            // 391 * 128, so GEMM needs no M bounds checks
#define KPHYS 1024            // A2 physical row width: [hi(512) | lo(512)]
#define KB 1024               // B2T physical row width: [hi(512) | lo(512)]
#define NOUTER 16             // 16 outer iters x 32 cols = 512 K
#define SCANB ((N_NODES + 255) / 256)  // 196 scan blocks

// ---------------- bf16 helpers ----------------

__device__ __forceinline__ unsigned short bf16_rn(float f) {
    unsigned u = __float_as_uint(f);
    u += 0x7FFFu + ((u >> 16) & 1u);  // round-to-nearest-even
    return (unsigned short)(u >> 16);
}
__device__ __forceinline__ float bf16_f32(unsigned short h) {
    return __uint_as_float(((unsigned)h) << 16);
}

// ---------------- nontemporal helpers ----------------

typedef __attribute__((ext_vector_type(4))) float f4v;
typedef __attribute__((ext_vector_type(2))) float f2v;

__device__ __forceinline__ float4 ntload4(const float* p) {
    f4v v = __builtin_nontemporal_load((const f4v*)p);
    return make_float4(v[0], v[1], v[2], v[3]);
}
__device__ __forceinline__ float2 ntload2(const float* p) {
    f2v v = __builtin_nontemporal_load((const f2v*)p);
    return make_float2(v[0], v[1]);
}

// ---------------- degree / CSR build ----------------

__global__ void zero_int_kernel(int* __restrict__ p, int n) {
    int i = blockIdx.x * blockDim.x + threadIdx.x;
    if (i < n) p[i] = 0;
}

__global__ void count_deg_kernel(const int* __restrict__ dst, int* __restrict__ deg) {
    int e = blockIdx.x * blockDim.x + threadIdx.x;
    if (e < N_EDGES) atomicAdd(&deg[dst[e]], 1);
}

__global__ void dinv_kernel(const int* __restrict__ deg, float* __restrict__ dinv) {
    int i = blockIdx.x * blockDim.x + threadIdx.x;
    if (i < N_NODES) dinv[i] = rsqrtf((float)deg[i] + 1.0f);  // +1 self-loop
}

// 3-kernel scan (multi-block; replaced the 1-CU serial scan)
__global__ __launch_bounds__(256) void scan1_kernel(const int* __restrict__ deg,
                                                    int* __restrict__ local_scan,
                                                    int* __restrict__ partials) {
    __shared__ int sm[256];
    int b = blockIdx.x, t = threadIdx.x;
    int i = b * 256 + t;
    int v = (i < N_NODES) ? deg[i] : 0;
    sm[t] = v;
    __syncthreads();
    for (int off = 1; off < 256; off <<= 1) {
        int x = (t >= off) ? sm[t - off] : 0;
        __syncthreads();
        sm[t] += x;
        __syncthreads();
    }
    if (i < N_NODES) local_scan[i] = sm[t];
    if (t == 255) partials[b] = sm[255];
}

__global__ __launch_bounds__(256) void scan2_kernel(int* __restrict__ partials) {
    __shared__ int sm[256];
    int t = threadIdx.x;
    sm[t] = (t < SCANB) ? partials[t] : 0;
    __syncthreads();
    for (int off = 1; off < 256; off <<= 1) {
        int x = (t >= off) ? sm[t - off] : 0;
        __syncthreads();
        sm[t] += x;
        __syncthreads();
    }
    if (t < SCANB) partials[t] = (t == 0) ? 0 : sm[t - 1];  // exclusive
}

__global__ __launch_bounds__(256) void scan3_kernel(const int* __restrict__ deg,
                                                    const int* __restrict__ local_scan,
                                                    const int* __restrict__ partials,
                                                    int* __restrict__ offsets,
                                                    int* __restrict__ cursor) {
    int i = blockIdx.x * 256 + threadIdx.x;
    if (i == 0) offsets[0] = 0;
    if (i < N_NODES) {
        int incl = local_scan[i] + partials[blockIdx.x];
        offsets[i + 1] = incl;
        cursor[i] = incl - deg[i];
    }
}

__global__ void fill_csr_kernel(const int* __restrict__ src, const int* __restrict__ dst,
                                int* __restrict__ cursor, int* __restrict__ csr_src,
                                float* __restrict__ csr_w, const float* __restrict__ dinv) {
    int e = blockIdx.x * blockDim.x + threadIdx.x;
    if (e < N_EDGES) {
        int s = src[e], d = dst[e];
        int p = atomicAdd(&cursor[d], 1);
        csr_src[p] = s;
        csr_w[p] = dinv[s] * dinv[d];
    }
}

// ---------------- split-bf16 MFMA GEMM (fp16 hi/lo output) ----------------
// One outer iteration stages {A_hi, A_lo, B_hi, B_lo} 32-col chunks and runs
// all three split passes (hi*hi, lo*hi, hi*lo) off that single staging.
// Output: C stored as fp16 hi + fp16 residual lo (4B/elem, was 6B). Keeps the
// aggregate's working set (Chi 51 + Clo 51 + A2 102 MB) under the 256MB L3 so
// the gather stops thrashing (R2 measured 438MB fetch vs 161 ideal).

typedef __attribute__((ext_vector_type(8))) short bf16x8;
typedef __attribute__((ext_vector_type(4))) float floatx4;

#define GLL16(g, l)                                                                   \
    __builtin_amdgcn_global_load_lds((__attribute__((address_space(1))) const void*)(g), \
                                     (__attribute__((address_space(3))) void*)(l), 16, 0, 0)

__global__ __launch_bounds__(256) void gemm_split_bt(const unsigned short* __restrict__ A2,
                                                     const unsigned short* __restrict__ B2T,
                                                     __half* __restrict__ Chi,
                                                     __half* __restrict__ Clo, int N) {
    // [buf][hi/lo] 128x32 chunks, double-buffered: 64 KiB total
    __shared__ unsigned short As[2][2][128 * 32];
    __shared__ unsigned short Bs[2][2][128 * 32];

    const int t = threadIdx.x;
    const int lane = t & 63;
    const int quad = lane >> 4;
    const int l15 = lane & 15;
    const int w = t >> 6;
    const int wm = w & 1, wn = w >> 1;
    const int row0 = blockIdx.y * 128;   // grid transposed: y = row band
    const int col0 = blockIdx.x * 128;   //                  x = col block

    floatx4 acc[4][4];
#pragma unroll
    for (int i = 0; i < 4; i++)
#pragma unroll
        for (int j = 0; j < 4; j++) acc[i][j] = (floatx4){0.f, 0.f, 0.f, 0.f};

    // coalesced staging with XOR-swizzled k-chunk
    const int sr = t >> 2;
    const int sk = ((t & 3) ^ ((t >> 3) & 3)) * 8;
    const unsigned short* Arow0 = A2 + (size_t)(row0 + sr) * KPHYS + sk;
    const unsigned short* Arow1 = Arow0 + (size_t)64 * KPHYS;
    const unsigned short* Brow0 = B2T + (size_t)(col0 + sr) * KB + sk;
    const unsigned short* Brow1 = Brow0 + (size_t)64 * KB;

    // fragment-read swizzle: chunk column = quad ^ ((l15>>1)&3)
    const int fcol = (quad ^ ((l15 >> 1) & 3)) * 8;

#define STAGE(buf, k32)                                            \
    do {                                                           \
        GLL16(Arow0 + (k32), As[buf][0] + t * 8);                  \
        GLL16(Arow1 + (k32), As[buf][0] + 2048 + t * 8);           \
        GLL16(Arow0 + 512 + (k32), As[buf][1] + t * 8);            \
        GLL16(Arow1 + 512 + (k32), As[buf][1] + 2048 + t * 8);     \
        GLL16(Brow0 + (k32), Bs[buf][0] + t * 8);                  \
        GLL16(Brow1 + (k32), Bs[buf][0] + 2048 + t * 8);           \
        GLL16(Brow0 + 512 + (k32), Bs[buf][1] + t * 8);            \
        GLL16(Brow1 + 512 + (k32), Bs[buf][1] + 2048 + t * 8);     \
    } while (0)

    // prologue: stage chunk 0 into buffer 0
    STAGE(0, 0);

    for (int it = 0; it < NOUTER; it++) {
        const int cur = it & 1;
        __syncthreads();  // drains prefetch into cur; all reads of cur^1 done
        if (it + 1 < NOUTER) STAGE(cur ^ 1, (it + 1) * 32);

        bf16x8 afh[4], afl[4], bfh[4], bfl[4];
#pragma unroll
        for (int mt = 0; mt < 4; mt++) {
            const int ro = (wm * 64 + mt * 16 + l15) * 32 + fcol;
            afh[mt] = *(const bf16x8*)(As[cur][0] + ro);
            afl[mt] = *(const bf16x8*)(As[cur][1] + ro);
        }
#pragma unroll
        for (int nt = 0; nt < 4; nt++) {
            const int ro = (wn * 64 + nt * 16 + l15) * 32 + fcol;
            bfh[nt] = *(const bf16x8*)(Bs[cur][0] + ro);
            bfl[nt] = *(const bf16x8*)(Bs[cur][1] + ro);
        }
        // pass 1: hi*hi
#pragma unroll
        for (int mt = 0; mt < 4; mt++)
#pragma unroll
            for (int nt = 0; nt < 4; nt++)
                acc[mt][nt] = __builtin_amdgcn_mfma_f32_16x16x32_bf16(afh[mt], bfh[nt], acc[mt][nt], 0, 0, 0);
        // pass 2: lo*hi
#pragma unroll
        for (int mt = 0; mt < 4; mt++)
#pragma unroll
            for (int nt = 0; nt < 4; nt++)
                acc[mt][nt] = __builtin_amdgcn_mfma_f32_16x16x32_bf16(afl[mt], bfh[nt], acc[mt][nt], 0, 0, 0);
        // pass 3: hi*lo
#pragma unroll
        for (int mt = 0; mt < 4; mt++)
#pragma unroll
            for (int nt = 0; nt < 4; nt++)
                acc[mt][nt] = __builtin_amdgcn_mfma_f32_16x16x32_bf16(afh[mt], bfl[nt], acc[mt][nt], 0, 0, 0);
    }
#undef STAGE

#pragma unroll
    for (int mt = 0; mt < 4; mt++) {
#pragma unroll
        for (int r = 0; r < 4; r++) {
            int row = row0 + wm * 64 + mt * 16 + quad * 4 + r;
            __half* Cph = Chi + (size_t)row * N + col0 + wn * 64 + l15;
            __half* Cpl = Clo + (size_t)row * N + col0 + wn * 64 + l15;
#pragma unroll
            for (int nt = 0; nt < 4; nt++) {
                float a = acc[mt][nt][r];
                __half hi = __float2half(a);
                __half lo = __float2half(a - __half2float(hi));
                Cph[nt * 16] = hi;
                Cpl[nt * 16] = lo;
            }
        }
    }
}

// ---------------- weight split (W [K x N] fp32 -> B2T [N x KB] bf16) ----------------

__global__ void wsplit_kernel(const float* __restrict__ W, unsigned short* __restrict__ B2T, int N) {
    int idx = blockIdx.x * blockDim.x + threadIdx.x;
    if (idx >= 512 * N) return;
    int k = idx / N, n = idx % N;
    float v = W[(size_t)k * N + n];
    unsigned short hi = bf16_rn(v);
    unsigned short lo = bf16_rn(v - bf16_f32(hi));
    unsigned short* row = B2T + (size_t)n * KB;
    row[k] = hi;
    row[512 + k] = lo;
}

// ---------------- x split (fp32 [N_NODES x 512] -> A2 [MPAD x KPHYS]) ----------------

__global__ __launch_bounds__(256) void split_x_kernel(const float* __restrict__ x,
                                                      unsigned short* __restrict__ A2) {
    int m = blockIdx.x;
    int ch = threadIdx.x * 2;
    unsigned short* arow = A2 + (size_t)m * KPHYS;
    float vx = 0.f, vy = 0.f;
    if (m < N_NODES) {
        float2 v = ntload2(x + (size_t)m * 512 + ch);  // x read exactly once
        vx = v.x;
        vy = v.y;
    }
    unsigned short hx = bf16_rn(vx), hy = bf16_rn(vy);
    arow[ch] = hx;
    arow[ch + 1] = hy;
    arow[512 + ch] = bf16_rn(vx - bf16_f32(hx));
    arow[512 + ch + 1] = bf16_rn(vy - bf16_f32(hy));
}

// ---------------- aggregation ----------------

__device__ __forceinline__ float gelu_tanh(float x) {
    float x3 = x * x * x;
    float inner = 0.7978845608028654f * (x + 0.044715f * x3);
    return 0.5f * x * (1.0f + tanhf(inner));
}

// One wave per node: 64 lanes x 8 fp16 ch = 512 ch. 4 nodes per 256-thread block.
// Gather from Chi (fp16, identical precision to old C16); self term = hi + lo
// residual (error ~2^-22 relative, as good as the old fp32 read at half bytes).
__global__ __launch_bounds__(256) void aggregate_split_kernel(
    const __half* __restrict__ Chi, const __half* __restrict__ Clo,
    const int* __restrict__ offsets, const int* __restrict__ csr_src,
    const float* __restrict__ csr_w, const float* __restrict__ dinv,
    const float* __restrict__ bias, unsigned short* __restrict__ A2) {
    int t = threadIdx.x;
    int node = __builtin_amdgcn_readfirstlane(blockIdx.x * 4 + (t >> 6));
    int ch = (t & 63) * 8;
    unsigned short* arow = A2 + (size_t)node * KPHYS;
    if (node >= N_NODES) {  // zero pad rows (16B per store)
        *(uint4*)(arow + ch) = make_uint4(0, 0, 0, 0);
        *(uint4*)(arow + 512 + ch) = make_uint4(0, 0, 0, 0);
        return;
    }
    int p0 = offsets[node], p1 = offsets[node + 1];
    float a[8] = {0.f, 0.f, 0.f, 0.f, 0.f, 0.f, 0.f, 0.f};

    union H8 { float4 f4; __half2 h2[4]; };
    int p = p0;
    int pend4 = p0 + ((p1 - p0) & ~3);
    for (; p < pend4; p += 4) {
        int s0 = csr_src[p], s1 = csr_src[p + 1], s2 = csr_src[p + 2], s3 = csr_src[p + 3];
        float w0 = csr_w[p], w1 = csr_w[p + 1], w2 = csr_w[p + 2], w3 = csr_w[p + 3];
        H8 v0, v1, v2, v3;
        v0.f4 = *(const float4*)(Chi + (size_t)s0 * 512 + ch);
        v1.f4 = *(const float4*)(Chi + (size_t)s1 * 512 + ch);
        v2.f4 = *(const float4*)(Chi + (size_t)s2 * 512 + ch);
        v3.f4 = *(const float4*)(Chi + (size_t)s3 * 512 + ch);
#pragma unroll
        for (int j = 0; j < 4; j++) {
            float2 c0 = __half22float2(v0.h2[j]);
            float2 c1 = __half22float2(v1.h2[j]);
            float2 c2 = __half22float2(v2.h2[j]);
            float2 c3 = __half22float2(v3.h2[j]);
            a[2 * j] += w0 * c0.x + w1 * c1.x + w2 * c2.x + w3 * c3.x;
            a[2 * j + 1] += w0 * c0.y + w1 * c1.y + w2 * c2.y + w3 * c3.y;
        }
    }
    for (; p < p1; p++) {
        int s = csr_src[p];
        float wg = csr_w[p];
        H8 v;
        v.f4 = *(const float4*)(Chi + (size_t)s * 512 + ch);
#pragma unroll
        for (int j = 0; j < 4; j++) {
            float2 c = __half22float2(v.h2[j]);
            a[2 * j] += wg * c.x;
            a[2 * j + 1] += wg * c.y;
        }
    }

    float di = dinv[node];
    float wself = di * di;
    H8 vh, vl;
    vh.f4 = *(const float4*)(Chi + (size_t)node * 512 + ch);
    vl.f4 = *(const float4*)(Clo + (size_t)node * 512 + ch);
    float4 bv0 = *(const float4*)(bias + ch);
    float4 bv1 = *(const float4*)(bias + ch + 4);
    float s[8], b[8] = {bv0.x, bv0.y, bv0.z, bv0.w, bv1.x, bv1.y, bv1.z, bv1.w};
#pragma unroll
    for (int j = 0; j < 4; j++) {
        float2 ch2 = __half22float2(vh.h2[j]);
        float2 cl2 = __half22float2(vl.h2[j]);
        s[2 * j] = ch2.x + cl2.x;
        s[2 * j + 1] = ch2.y + cl2.y;
    }

    unsigned short hi[8], lo[8];
#pragma unroll
    for (int j = 0; j < 8; j++) {
        float v = gelu_tanh(a[j] + wself * s[j] + b[j]);
        hi[j] = bf16_rn(v);
        lo[j] = bf16_rn(v - bf16_f32(hi[j]));
    }
    *(ushort4*)(arow + ch) = make_ushort4(hi[0], hi[1], hi[2], hi[3]);
    *(ushort4*)(arow + ch + 4) = make_ushort4(hi[4], hi[5], hi[6], hi[7]);
    *(ushort4*)(arow + 512 + ch) = make_ushort4(lo[0], lo[1], lo[2], lo[3]);
    *(ushort4*)(arow + 512 + ch + 4) = make_ushort4(lo[4], lo[5], lo[6], lo[7]);
}

// Final agg: 256 ch, one wave per node (64 lanes x 4 fp16 ch), 4 nodes/block.
__global__ __launch_bounds__(256) void aggregate_final_kernel(
    const __half* __restrict__ Chi, const __half* __restrict__ Clo,
    const int* __restrict__ offsets, const int* __restrict__ csr_src,
    const float* __restrict__ csr_w, const float* __restrict__ dinv,
    const float* __restrict__ bias, float* __restrict__ out) {
    int t = threadIdx.x;
    int node = __builtin_amdgcn_readfirstlane(blockIdx.x * 4 + (t >> 6));
    if (node >= N_NODES) return;
    int ch = (t & 63) * 4;
    int p0 = offsets[node], p1 = offsets[node + 1];
    float ax = 0.f, ay = 0.f, az = 0.f, aw = 0.f;

    union H4 { float2 f2; __half2 h2[2]; };
    int p = p0;
    int pend4 = p0 + ((p1 - p0) & ~3);
    for (; p < pend4; p += 4) {
        int s0 = csr_src[p], s1 = csr_src[p + 1], s2 = csr_src[p + 2], s3 = csr_src[p + 3];
        float w0 = csr_w[p], w1 = csr_w[p + 1], w2 = csr_w[p + 2], w3 = csr_w[p + 3];
        H4 v0, v1, v2, v3;
        v0.f2 = *(const float2*)(Chi + (size_t)s0 * 256 + ch);
        v1.f2 = *(const float2*)(Chi + (size_t)s1 * 256 + ch);
        v2.f2 = *(const float2*)(Chi + (size_t)s2 * 256 + ch);
        v3.f2 = *(const float2*)(Chi + (size_t)s3 * 256 + ch);
        float2 c00 = __half22float2(v0.h2[0]), c01 = __half22float2(v0.h2[1]);
        float2 c10 = __half22float2(v1.h2[0]), c11 = __half22float2(v1.h2[1]);
        float2 c20 = __half22float2(v2.h2[0]), c21 = __half22float2(v2.h2[1]);
        float2 c30 = __half22float2(v3.h2[0]), c31 = __half22float2(v3.h2[1]);
        ax += w0 * c00.x + w1 * c10.x + w2 * c20.x + w3 * c30.x;
        ay += w0 * c00.y + w1 * c10.y + w2 * c20.y + w3 * c30.y;
        az += w0 * c01.x + w1 * c11.x + w2 * c21.x + w3 * c31.x;
        aw += w0 * c01.y + w1 * c11.y + w2 * c21.y + w3 * c31.y;
    }
    for (; p < p1; p++) {
        int s = csr_src[p];
        float wg = csr_w[p];
        H4 v;
        v.f2 = *(const float2*)(Chi + (size_t)s * 256 + ch);
        float2 c0 = __half22float2(v.h2[0]), c1 = __half22float2(v.h2[1]);
        ax += wg * c0.x; ay += wg * c0.y; az += wg * c1.x; aw += wg * c1.y;
    }

    float di = dinv[node];
    float wself = di * di;
    H4 vh, vl;
    vh.f2 = *(const float2*)(Chi + (size_t)node * 256 + ch);
    vl.f2 = *(const float2*)(Clo + (size_t)node * 256 + ch);
    float2 h0 = __half22float2(vh.h2[0]), h1 = __half22float2(vh.h2[1]);
    float2 l0 = __half22float2(vl.h2[0]), l1 = __half22float2(vl.h2[1]);
    float4 bv = *(const float4*)(bias + ch);
    float4 o = make_float4(ax + wself * (h0.x + l0.x) + bv.x,
                           ay + wself * (h0.y + l0.y) + bv.y,
                           az + wself * (h1.x + l1.x) + bv.z,
                           aw + wself * (h1.y + l1.y) + bv.w);
    *(float4*)(out + (size_t)node * 256 + ch) = o;
}

// ---------------- launch ----------------

static inline char* align16(char* p) { return (char*)(((size_t)p + 15) & ~(size_t)15); }

extern "C" void kernel_launch(void* const* d_in, const int* in_sizes, int n_in,
                              void* d_out, int out_size, void* d_ws, size_t ws_size,
                              hipStream_t stream) {
    const float* x  = (const float*)d_in[0];
    const int* eidx = (const int*)d_in[1];
    const float* W1 = (const float*)d_in[2];
    const float* b1 = (const float*)d_in[3];
    const float* W2 = (const float*)d_in[4];
    const float* b2 = (const float*)d_in[5];
    const float* W3 = (const float*)d_in[6];
    const float* b3 = (const float*)d_in[7];
    float* out = (float*)d_out;

    const int* src = eidx;
    const int* dst = eidx + N_EDGES;

    char* ws = (char*)d_ws;
    unsigned short* A2 = (unsigned short*)ws;  ws += (size_t)MPAD * KPHYS * 2;   // 102.5 MB
    __half* Chi = (__half*)ws;                 ws += (size_t)MPAD * 512 * 2;      // 51.2 MB
    __half* Clo = (__half*)ws;                 ws += (size_t)MPAD * 512 * 2;      // 51.2 MB
    unsigned short* B2T1 = (unsigned short*)ws; ws += (size_t)512 * KB * 2;
    unsigned short* B2T2 = (unsigned short*)ws; ws += (size_t)512 * KB * 2;
    unsigned short* B2T3 = (unsigned short*)ws; ws += (size_t)256 * KB * 2;
    int* deg = (int*)ws;        ws = align16(ws + (size_t)N_NODES * 4);
    float* dinv = (float*)ws;   ws = align16(ws + (size_t)N_NODES * 4);
    int* offsets = (int*)ws;    ws = align16(ws + (size_t)(N_NODES + 1) * 4);
    int* cursor = (int*)ws;     ws = align16(ws + (size_t)N_NODES * 4);
    int* csr_src = (int*)ws;    ws = align16(ws + (size_t)N_EDGES * 4);
    float* csr_w = (float*)ws;  ws = align16(ws + (size_t)N_EDGES * 4);
    int* local_scan = (int*)ws; ws = align16(ws + (size_t)N_NODES * 4);
    int* partials = (int*)ws;   ws = align16(ws + (size_t)SCANB * 4);

    // ---- CSR build ----
    zero_int_kernel<<<(N_NODES + 255) / 256, 256, 0, stream>>>(deg, N_NODES);
    count_deg_kernel<<<(N_EDGES + 255) / 256, 256, 0, stream>>>(dst, deg);
    dinv_kernel<<<(N_NODES + 255) / 256, 256, 0, stream>>>(deg, dinv);
    scan1_kernel<<<SCANB, 256, 0, stream>>>(deg, local_scan, partials);
    scan2_kernel<<<1, 256, 0, stream>>>(partials);
    scan3_kernel<<<SCANB, 256, 0, stream>>>(deg, local_scan, partials, offsets, cursor);
    fill_csr_kernel<<<(N_EDGES + 255) / 256, 256, 0, stream>>>(src, dst, cursor, csr_src, csr_w, dinv);

    // ---- weight + input splits ----
    wsplit_kernel<<<(512 * 512 + 255) / 256, 256, 0, stream>>>(W1, B2T1, 512);
    wsplit_kernel<<<(512 * 512 + 255) / 256, 256, 0, stream>>>(W2, B2T2, 512);
    wsplit_kernel<<<(512 * 256 + 255) / 256, 256, 0, stream>>>(W3, B2T3, 256);
    split_x_kernel<<<MPAD, 256, 0, stream>>>(x, A2);

    // ---- layer 1 ----
    {
        dim3 grid(512 / 128, MPAD / 128);  // x = col block, y = row band
        gemm_split_bt<<<grid, 256, 0, stream>>>(A2, B2T1, Chi, Clo, 512);
        aggregate_split_kernel<<<MPAD / 4, 256, 0, stream>>>(Chi, Clo, offsets, csr_src, csr_w, dinv, b1, A2);
    }
    // ---- layer 2 ----
    {
        dim3 grid(512 / 128, MPAD / 128);
        gemm_split_bt<<<grid, 256, 0, stream>>>(A2, B2T2, Chi, Clo, 512);
        aggregate_split_kernel<<<MPAD / 4, 256, 0, stream>>>(Chi, Clo, offsets, csr_src, csr_w, dinv, b2, A2);
    }
    // ---- layer 3 ----
    {
        dim3 grid(256 / 128, MPAD / 128);
        gemm_split_bt<<<grid, 256, 0, stream>>>(A2, B2T3, Chi, Clo, 256);
        aggregate_final_kernel<<<MPAD / 4, 256, 0, stream>>>(Chi, Clo, offsets, csr_src, csr_w, dinv, b3, out);
    }
}

// Round 4
// 900.580 us; speedup vs baseline: 1.2218x; 1.0214x over previous
//
#include <hip/hip_runtime.h>
#include <hip/hip_fp16.h>
#include <math.h>

#define N_NODES 50000
#define N_EDGES 800000
#define MPAD 50048            // 391 * 128, so GEMM needs no M bounds checks
#define KPHYS 1024            // A2 physical row width: [hi(512) | lo(512)]
#define KB 1024               // B2T physical row width: [hi(512) | lo(512)]
#define NOUTER 16             // 16 outer iters x 32 cols = 512 K
#define SCANB ((N_NODES + 255) / 256)  // 196 scan blocks

// ---------------- bf16 helpers ----------------

__device__ __forceinline__ unsigned short bf16_rn(float f) {
    unsigned u = __float_as_uint(f);
    u += 0x7FFFu + ((u >> 16) & 1u);  // round-to-nearest-even
    return (unsigned short)(u >> 16);
}
__device__ __forceinline__ float bf16_f32(unsigned short h) {
    return __uint_as_float(((unsigned)h) << 16);
}

typedef __attribute__((ext_vector_type(2))) float f2v;

__device__ __forceinline__ float2 ntload2(const float* p) {
    f2v v = __builtin_nontemporal_load((const f2v*)p);
    return make_float2(v[0], v[1]);
}

// ---------------- degree / CSR build ----------------

__global__ void zero_int_kernel(int* __restrict__ p, int n) {
    int i = blockIdx.x * blockDim.x + threadIdx.x;
    if (i < n) p[i] = 0;
}

__global__ void count_deg_kernel(const int* __restrict__ dst, int* __restrict__ deg) {
    int e = blockIdx.x * blockDim.x + threadIdx.x;
    if (e < N_EDGES) atomicAdd(&deg[dst[e]], 1);
}

__global__ void dinv_kernel(const int* __restrict__ deg, float* __restrict__ dinv) {
    int i = blockIdx.x * blockDim.x + threadIdx.x;
    if (i < N_NODES) dinv[i] = rsqrtf((float)deg[i] + 1.0f);  // +1 self-loop
}

// 3-kernel scan (multi-block)
__global__ __launch_bounds__(256) void scan1_kernel(const int* __restrict__ deg,
                                                    int* __restrict__ local_scan,
                                                    int* __restrict__ partials) {
    __shared__ int sm[256];
    int b = blockIdx.x, t = threadIdx.x;
    int i = b * 256 + t;
    int v = (i < N_NODES) ? deg[i] : 0;
    sm[t] = v;
    __syncthreads();
    for (int off = 1; off < 256; off <<= 1) {
        int x = (t >= off) ? sm[t - off] : 0;
        __syncthreads();
        sm[t] += x;
        __syncthreads();
    }
    if (i < N_NODES) local_scan[i] = sm[t];
    if (t == 255) partials[b] = sm[255];
}

__global__ __launch_bounds__(256) void scan2_kernel(int* __restrict__ partials) {
    __shared__ int sm[256];
    int t = threadIdx.x;
    sm[t] = (t < SCANB) ? partials[t] : 0;
    __syncthreads();
    for (int off = 1; off < 256; off <<= 1) {
        int x = (t >= off) ? sm[t - off] : 0;
        __syncthreads();
        sm[t] += x;
        __syncthreads();
    }
    if (t < SCANB) partials[t] = (t == 0) ? 0 : sm[t - 1];  // exclusive
}

__global__ __launch_bounds__(256) void scan3_kernel(const int* __restrict__ deg,
                                                    const int* __restrict__ local_scan,
                                                    const int* __restrict__ partials,
                                                    int* __restrict__ offsets,
                                                    int* __restrict__ cursor) {
    int i = blockIdx.x * 256 + threadIdx.x;
    if (i == 0) offsets[0] = 0;
    if (i < N_NODES) {
        int incl = local_scan[i] + partials[blockIdx.x];
        offsets[i + 1] = incl;
        cursor[i] = incl - deg[i];
    }
}

// packed CSR entry: {src, weight-as-bits} -> one 8B load per edge
__global__ void fill_csr_kernel(const int* __restrict__ src, const int* __restrict__ dst,
                                int* __restrict__ cursor, int2* __restrict__ csr_sw,
                                const float* __restrict__ dinv) {
    int e = blockIdx.x * blockDim.x + threadIdx.x;
    if (e < N_EDGES) {
        int s = src[e], d = dst[e];
        int p = atomicAdd(&cursor[d], 1);
        csr_sw[p] = make_int2(s, __float_as_int(dinv[s] * dinv[d]));
    }
}

// ---------------- split-bf16 MFMA GEMM (fp16 hi/lo output) ----------------

typedef __attribute__((ext_vector_type(8))) short bf16x8;
typedef __attribute__((ext_vector_type(4))) float floatx4;

#define GLL16(g, l)                                                                   \
    __builtin_amdgcn_global_load_lds((__attribute__((address_space(1))) const void*)(g), \
                                     (__attribute__((address_space(3))) void*)(l), 16, 0, 0)

__global__ __launch_bounds__(256) void gemm_split_bt(const unsigned short* __restrict__ A2,
                                                     const unsigned short* __restrict__ B2T,
                                                     __half* __restrict__ Chi,
                                                     __half* __restrict__ Clo, int N) {
    // [buf][hi/lo] 128x32 chunks, double-buffered: 64 KiB total
    __shared__ unsigned short As[2][2][128 * 32];
    __shared__ unsigned short Bs[2][2][128 * 32];

    const int t = threadIdx.x;
    const int lane = t & 63;
    const int quad = lane >> 4;
    const int l15 = lane & 15;
    const int w = t >> 6;
    const int wm = w & 1, wn = w >> 1;
    const int row0 = blockIdx.y * 128;   // grid transposed: y = row band
    const int col0 = blockIdx.x * 128;   //                  x = col block

    floatx4 acc[4][4];
#pragma unroll
    for (int i = 0; i < 4; i++)
#pragma unroll
        for (int j = 0; j < 4; j++) acc[i][j] = (floatx4){0.f, 0.f, 0.f, 0.f};

    // coalesced staging with XOR-swizzled k-chunk
    const int sr = t >> 2;
    const int sk = ((t & 3) ^ ((t >> 3) & 3)) * 8;
    const unsigned short* Arow0 = A2 + (size_t)(row0 + sr) * KPHYS + sk;
    const unsigned short* Arow1 = Arow0 + (size_t)64 * KPHYS;
    const unsigned short* Brow0 = B2T + (size_t)(col0 + sr) * KB + sk;
    const unsigned short* Brow1 = Brow0 + (size_t)64 * KB;

    // fragment-read swizzle: chunk column = quad ^ ((l15>>1)&3)
    const int fcol = (quad ^ ((l15 >> 1) & 3)) * 8;

#define STAGE(buf, k32)                                            \
    do {                                                           \
        GLL16(Arow0 + (k32), As[buf][0] + t * 8);                  \
        GLL16(Arow1 + (k32), As[buf][0] + 2048 + t * 8);           \
        GLL16(Arow0 + 512 + (k32), As[buf][1] + t * 8);            \
        GLL16(Arow1 + 512 + (k32), As[buf][1] + 2048 + t * 8);     \
        GLL16(Brow0 + (k32), Bs[buf][0] + t * 8);                  \
        GLL16(Brow1 + (k32), Bs[buf][0] + 2048 + t * 8);           \
        GLL16(Brow0 + 512 + (k32), Bs[buf][1] + t * 8);            \
        GLL16(Brow1 + 512 + (k32), Bs[buf][1] + 2048 + t * 8);     \
    } while (0)

    // prologue: stage chunk 0 into buffer 0
    STAGE(0, 0);

    for (int it = 0; it < NOUTER; it++) {
        const int cur = it & 1;
        __syncthreads();  // drains prefetch into cur; all reads of cur^1 done
        if (it + 1 < NOUTER) STAGE(cur ^ 1, (it + 1) * 32);

        bf16x8 afh[4], afl[4], bfh[4], bfl[4];
#pragma unroll
        for (int mt = 0; mt < 4; mt++) {
            const int ro = (wm * 64 + mt * 16 + l15) * 32 + fcol;
            afh[mt] = *(const bf16x8*)(As[cur][0] + ro);
            afl[mt] = *(const bf16x8*)(As[cur][1] + ro);
        }
#pragma unroll
        for (int nt = 0; nt < 4; nt++) {
            const int ro = (wn * 64 + nt * 16 + l15) * 32 + fcol;
            bfh[nt] = *(const bf16x8*)(Bs[cur][0] + ro);
            bfl[nt] = *(const bf16x8*)(Bs[cur][1] + ro);
        }
        // pass 1: hi*hi
#pragma unroll
        for (int mt = 0; mt < 4; mt++)
#pragma unroll
            for (int nt = 0; nt < 4; nt++)
                acc[mt][nt] = __builtin_amdgcn_mfma_f32_16x16x32_bf16(afh[mt], bfh[nt], acc[mt][nt], 0, 0, 0);
        // pass 2: lo*hi
#pragma unroll
        for (int mt = 0; mt < 4; mt++)
#pragma unroll
            for (int nt = 0; nt < 4; nt++)
                acc[mt][nt] = __builtin_amdgcn_mfma_f32_16x16x32_bf16(afl[mt], bfh[nt], acc[mt][nt], 0, 0, 0);
        // pass 3: hi*lo
#pragma unroll
        for (int mt = 0; mt < 4; mt++)
#pragma unroll
            for (int nt = 0; nt < 4; nt++)
                acc[mt][nt] = __builtin_amdgcn_mfma_f32_16x16x32_bf16(afh[mt], bfl[nt], acc[mt][nt], 0, 0, 0);
    }
#undef STAGE

#pragma unroll
    for (int mt = 0; mt < 4; mt++) {
#pragma unroll
        for (int r = 0; r < 4; r++) {
            int row = row0 + wm * 64 + mt * 16 + quad * 4 + r;
            __half* Cph = Chi + (size_t)row * N + col0 + wn * 64 + l15;
            __half* Cpl = Clo + (size_t)row * N + col0 + wn * 64 + l15;
#pragma unroll
            for (int nt = 0; nt < 4; nt++) {
                float a = acc[mt][nt][r];
                __half hi = __float2half(a);
                __half lo = __float2half(a - __half2float(hi));
                Cph[nt * 16] = hi;
                Cpl[nt * 16] = lo;
            }
        }
    }
}

// ---------------- weight split (W [K x N] fp32 -> B2T [N x KB] bf16) ----------------

__global__ void wsplit_kernel(const float* __restrict__ W, unsigned short* __restrict__ B2T, int N) {
    int idx = blockIdx.x * blockDim.x + threadIdx.x;
    if (idx >= 512 * N) return;
    int k = idx / N, n = idx % N;
    float v = W[(size_t)k * N + n];
    unsigned short hi = bf16_rn(v);
    unsigned short lo = bf16_rn(v - bf16_f32(hi));
    unsigned short* row = B2T + (size_t)n * KB;
    row[k] = hi;
    row[512 + k] = lo;
}

// ---------------- x split (fp32 [N_NODES x 512] -> A2 [MPAD x KPHYS]) ----------------

__global__ __launch_bounds__(256) void split_x_kernel(const float* __restrict__ x,
                                                      unsigned short* __restrict__ A2) {
    int m = blockIdx.x;
    int ch = threadIdx.x * 2;
    unsigned short* arow = A2 + (size_t)m * KPHYS;
    float vx = 0.f, vy = 0.f;
    if (m < N_NODES) {
        float2 v = ntload2(x + (size_t)m * 512 + ch);  // x read exactly once
        vx = v.x;
        vy = v.y;
    }
    unsigned short hx = bf16_rn(vx), hy = bf16_rn(vy);
    arow[ch] = hx;
    arow[ch + 1] = hy;
    arow[512 + ch] = bf16_rn(vx - bf16_f32(hx));
    arow[512 + ch + 1] = bf16_rn(vy - bf16_f32(hy));
}

// ---------------- aggregation ----------------

__device__ __forceinline__ float gelu_tanh(float x) {
    float x3 = x * x * x;
    float inner = 0.7978845608028654f * (x + 0.044715f * x3);
    return 0.5f * x * (1.0f + tanhf(inner));
}

// One wave per node: 64 lanes x 8 fp16 ch = 512 ch. 4 nodes per 256-thread block.
// R3: latency-bound fix — 8-deep gather unroll (8 outstanding row-gathers/wave,
// was 4) + packed int2 CSR (one 8B uniform load per edge, was 2x4B).
__global__ __launch_bounds__(256) void aggregate_split_kernel(
    const __half* __restrict__ Chi, const __half* __restrict__ Clo,
    const int* __restrict__ offsets, const int2* __restrict__ csr_sw,
    const float* __restrict__ dinv,
    const float* __restrict__ bias, unsigned short* __restrict__ A2) {
    int t = threadIdx.x;
    int node = __builtin_amdgcn_readfirstlane(blockIdx.x * 4 + (t >> 6));
    int ch = (t & 63) * 8;
    unsigned short* arow = A2 + (size_t)node * KPHYS;
    if (node >= N_NODES) {  // zero pad rows (16B per store)
        *(uint4*)(arow + ch) = make_uint4(0, 0, 0, 0);
        *(uint4*)(arow + 512 + ch) = make_uint4(0, 0, 0, 0);
        return;
    }
    int p0 = offsets[node], p1 = offsets[node + 1];
    float a[8] = {0.f, 0.f, 0.f, 0.f, 0.f, 0.f, 0.f, 0.f};

    union H8 { float4 f4; __half2 h2[4]; };
    int p = p0;
    int pend8 = p0 + ((p1 - p0) & ~7);
    for (; p < pend8; p += 8) {
        int2 e[8];
#pragma unroll
        for (int j = 0; j < 8; j++) e[j] = csr_sw[p + j];
        H8 v[8];
#pragma unroll
        for (int j = 0; j < 8; j++)
            v[j].f4 = *(const float4*)(Chi + (size_t)e[j].x * 512 + ch);
#pragma unroll
        for (int j = 0; j < 8; j++) {
            float wg = __int_as_float(e[j].y);
#pragma unroll
            for (int q = 0; q < 4; q++) {
                float2 c = __half22float2(v[j].h2[q]);
                a[2 * q] += wg * c.x;
                a[2 * q + 1] += wg * c.y;
            }
        }
    }
    if (p + 4 <= p1) {
        int2 e[4];
#pragma unroll
        for (int j = 0; j < 4; j++) e[j] = csr_sw[p + j];
        H8 v[4];
#pragma unroll
        for (int j = 0; j < 4; j++)
            v[j].f4 = *(const float4*)(Chi + (size_t)e[j].x * 512 + ch);
#pragma unroll
        for (int j = 0; j < 4; j++) {
            float wg = __int_as_float(e[j].y);
#pragma unroll
            for (int q = 0; q < 4; q++) {
                float2 c = __half22float2(v[j].h2[q]);
                a[2 * q] += wg * c.x;
                a[2 * q + 1] += wg * c.y;
            }
        }
        p += 4;
    }
    for (; p < p1; p++) {
        int2 e = csr_sw[p];
        float wg = __int_as_float(e.y);
        H8 v;
        v.f4 = *(const float4*)(Chi + (size_t)e.x * 512 + ch);
#pragma unroll
        for (int q = 0; q < 4; q++) {
            float2 c = __half22float2(v.h2[q]);
            a[2 * q] += wg * c.x;
            a[2 * q + 1] += wg * c.y;
        }
    }

    float di = dinv[node];
    float wself = di * di;
    H8 vh, vl;
    vh.f4 = *(const float4*)(Chi + (size_t)node * 512 + ch);
    vl.f4 = *(const float4*)(Clo + (size_t)node * 512 + ch);
    float4 bv0 = *(const float4*)(bias + ch);
    float4 bv1 = *(const float4*)(bias + ch + 4);
    float s[8], b[8] = {bv0.x, bv0.y, bv0.z, bv0.w, bv1.x, bv1.y, bv1.z, bv1.w};
#pragma unroll
    for (int j = 0; j < 4; j++) {
        float2 ch2 = __half22float2(vh.h2[j]);
        float2 cl2 = __half22float2(vl.h2[j]);
        s[2 * j] = ch2.x + cl2.x;
        s[2 * j + 1] = ch2.y + cl2.y;
    }

    unsigned short hi[8], lo[8];
#pragma unroll
    for (int j = 0; j < 8; j++) {
        float v = gelu_tanh(a[j] + wself * s[j] + b[j]);
        hi[j] = bf16_rn(v);
        lo[j] = bf16_rn(v - bf16_f32(hi[j]));
    }
    *(ushort4*)(arow + ch) = make_ushort4(hi[0], hi[1], hi[2], hi[3]);
    *(ushort4*)(arow + ch + 4) = make_ushort4(hi[4], hi[5], hi[6], hi[7]);
    *(ushort4*)(arow + 512 + ch) = make_ushort4(lo[0], lo[1], lo[2], lo[3]);
    *(ushort4*)(arow + 512 + ch + 4) = make_ushort4(lo[4], lo[5], lo[6], lo[7]);
}

// Final agg: 256 ch, one wave per node (64 lanes x 4 fp16 ch), 4 nodes/block.
__global__ __launch_bounds__(256) void aggregate_final_kernel(
    const __half* __restrict__ Chi, const __half* __restrict__ Clo,
    const int* __restrict__ offsets, const int2* __restrict__ csr_sw,
    const float* __restrict__ dinv,
    const float* __restrict__ bias, float* __restrict__ out) {
    int t = threadIdx.x;
    int node = __builtin_amdgcn_readfirstlane(blockIdx.x * 4 + (t >> 6));
    if (node >= N_NODES) return;
    int ch = (t & 63) * 4;
    int p0 = offsets[node], p1 = offsets[node + 1];
    float ax = 0.f, ay = 0.f, az = 0.f, aw = 0.f;

    union H4 { float2 f2; __half2 h2[2]; };
    int p = p0;
    int pend8 = p0 + ((p1 - p0) & ~7);
    for (; p < pend8; p += 8) {
        int2 e[8];
#pragma unroll
        for (int j = 0; j < 8; j++) e[j] = csr_sw[p + j];
        H4 v[8];
#pragma unroll
        for (int j = 0; j < 8; j++)
            v[j].f2 = *(const float2*)(Chi + (size_t)e[j].x * 256 + ch);
#pragma unroll
        for (int j = 0; j < 8; j++) {
            float wg = __int_as_float(e[j].y);
            float2 c0 = __half22float2(v[j].h2[0]), c1 = __half22float2(v[j].h2[1]);
            ax += wg * c0.x; ay += wg * c0.y; az += wg * c1.x; aw += wg * c1.y;
        }
    }
    for (; p < p1; p++) {
        int2 e = csr_sw[p];
        float wg = __int_as_float(e.y);
        H4 v;
        v.f2 = *(const float2*)(Chi + (size_t)e.x * 256 + ch);
        float2 c0 = __half22float2(v.h2[0]), c1 = __half22float2(v.h2[1]);
        ax += wg * c0.x; ay += wg * c0.y; az += wg * c1.x; aw += wg * c1.y;
    }

    float di = dinv[node];
    float wself = di * di;
    H4 vh, vl;
    vh.f2 = *(const float2*)(Chi + (size_t)node * 256 + ch);
    vl.f2 = *(const float2*)(Clo + (size_t)node * 256 + ch);
    float2 h0 = __half22float2(vh.h2[0]), h1 = __half22float2(vh.h2[1]);
    float2 l0 = __half22float2(vl.h2[0]), l1 = __half22float2(vl.h2[1]);
    float4 bv = *(const float4*)(bias + ch);
    float4 o = make_float4(ax + wself * (h0.x + l0.x) + bv.x,
                           ay + wself * (h0.y + l0.y) + bv.y,
                           az + wself * (h1.x + l1.x) + bv.z,
                           aw + wself * (h1.y + l1.y) + bv.w);
    *(float4*)(out + (size_t)node * 256 + ch) = o;
}

// ---------------- launch ----------------

static inline char* align16(char* p) { return (char*)(((size_t)p + 15) & ~(size_t)15); }

extern "C" void kernel_launch(void* const* d_in, const int* in_sizes, int n_in,
                              void* d_out, int out_size, void* d_ws, size_t ws_size,
                              hipStream_t stream) {
    const float* x  = (const float*)d_in[0];
    const int* eidx = (const int*)d_in[1];
    const float* W1 = (const float*)d_in[2];
    const float* b1 = (const float*)d_in[3];
    const float* W2 = (const float*)d_in[4];
    const float* b2 = (const float*)d_in[5];
    const float* W3 = (const float*)d_in[6];
    const float* b3 = (const float*)d_in[7];
    float* out = (float*)d_out;

    const int* src = eidx;
    const int* dst = eidx + N_EDGES;

    char* ws = (char*)d_ws;
    unsigned short* A2 = (unsigned short*)ws;  ws += (size_t)MPAD * KPHYS * 2;   // 102.5 MB
    __half* Chi = (__half*)ws;                 ws += (size_t)MPAD * 512 * 2;      // 51.2 MB
    __half* Clo = (__half*)ws;                 ws += (size_t)MPAD * 512 * 2;      // 51.2 MB
    unsigned short* B2T1 = (unsigned short*)ws; ws += (size_t)512 * KB * 2;
    unsigned short* B2T2 = (unsigned short*)ws; ws += (size_t)512 * KB * 2;
    unsigned short* B2T3 = (unsigned short*)ws; ws += (size_t)256 * KB * 2;
    int* deg = (int*)ws;        ws = align16(ws + (size_t)N_NODES * 4);
    float* dinv = (float*)ws;   ws = align16(ws + (size_t)N_NODES * 4);
    int* offsets = (int*)ws;    ws = align16(ws + (size_t)(N_NODES + 1) * 4);
    int* cursor = (int*)ws;     ws = align16(ws + (size_t)N_NODES * 4);
    int2* csr_sw = (int2*)ws;   ws = align16(ws + (size_t)N_EDGES * 8);
    int* local_scan = (int*)ws; ws = align16(ws + (size_t)N_NODES * 4);
    int* partials = (int*)ws;   ws = align16(ws + (size_t)SCANB * 4);

    // ---- CSR build ----
    zero_int_kernel<<<(N_NODES + 255) / 256, 256, 0, stream>>>(deg, N_NODES);
    count_deg_kernel<<<(N_EDGES + 255) / 256, 256, 0, stream>>>(dst, deg);
    dinv_kernel<<<(N_NODES + 255) / 256, 256, 0, stream>>>(deg, dinv);
    scan1_kernel<<<SCANB, 256, 0, stream>>>(deg, local_scan, partials);
    scan2_kernel<<<1, 256, 0, stream>>>(partials);
    scan3_kernel<<<SCANB, 256, 0, stream>>>(deg, local_scan, partials, offsets, cursor);
    fill_csr_kernel<<<(N_EDGES + 255) / 256, 256, 0, stream>>>(src, dst, cursor, csr_sw, dinv);

    // ---- weight + input splits ----
    wsplit_kernel<<<(512 * 512 + 255) / 256, 256, 0, stream>>>(W1, B2T1, 512);
    wsplit_kernel<<<(512 * 512 + 255) / 256, 256, 0, stream>>>(W2, B2T2, 512);
    wsplit_kernel<<<(512 * 256 + 255) / 256, 256, 0, stream>>>(W3, B2T3, 256);
    split_x_kernel<<<MPAD, 256, 0, stream>>>(x, A2);

    // ---- layer 1 ----
    {
        dim3 grid(512 / 128, MPAD / 128);  // x = col block, y = row band
        gemm_split_bt<<<grid, 256, 0, stream>>>(A2, B2T1, Chi, Clo, 512);
        aggregate_split_kernel<<<MPAD / 4, 256, 0, stream>>>(Chi, Clo, offsets, csr_sw, dinv, b1, A2);
    }
    // ---- layer 2 ----
    {
        dim3 grid(512 / 128, MPAD / 128);
        gemm_split_bt<<<grid, 256, 0, stream>>>(A2, B2T2, Chi, Clo, 512);
        aggregate_split_kernel<<<MPAD / 4, 256, 0, stream>>>(Chi, Clo, offsets, csr_sw, dinv, b2, A2);
    }
    // ---- layer 3 ----
    {
        dim3 grid(256 / 128, MPAD / 128);
        gemm_split_bt<<<grid, 256, 0, stream>>>(A2, B2T3, Chi, Clo, 256);
        aggregate_final_kernel<<<MPAD / 4, 256, 0, stream>>>(Chi, Clo, offsets, csr_sw, dinv, b3, out);
    }
}

// Round 5
// 883.514 us; speedup vs baseline: 1.2454x; 1.0193x over previous
//
#include <hip/hip_runtime.h>
#include <hip/hip_fp16.h>
#include <math.h>

#define N_NODES 50000
#define N_EDGES 800000
#define MPAD 50048            // 391 * 128, so GEMM needs no M bounds checks
#define NBANDS (MPAD / 128)   // 391 row bands
#define KPHYS 1024            // A2 physical row width: [hi(512) | lo(512)]
#define KB 1024               // B2T physical row width: [hi(512) | lo(512)]
#define NOUTER 16             // 16 outer iters x 32 cols = 512 K
#define SCANB ((N_NODES + 255) / 256)  // 196 scan blocks

// ---------------- bf16 helpers ----------------

__device__ __forceinline__ unsigned short bf16_rn(float f) {
    unsigned u = __float_as_uint(f);
    u += 0x7FFFu + ((u >> 16) & 1u);  // round-to-nearest-even
    return (unsigned short)(u >> 16);
}
__device__ __forceinline__ float bf16_f32(unsigned short h) {
    return __uint_as_float(((unsigned)h) << 16);
}

typedef __attribute__((ext_vector_type(2))) float f2v;

__device__ __forceinline__ float2 ntload2(const float* p) {
    f2v v = __builtin_nontemporal_load((const f2v*)p);
    return make_float2(v[0], v[1]);
}

// ---------------- degree / CSR build ----------------

__global__ void zero_int_kernel(int* __restrict__ p, int n) {
    int i = blockIdx.x * blockDim.x + threadIdx.x;
    if (i < n) p[i] = 0;
}

__global__ void count_deg_kernel(const int* __restrict__ dst, int* __restrict__ deg) {
    int e = blockIdx.x * blockDim.x + threadIdx.x;
    if (e < N_EDGES) atomicAdd(&deg[dst[e]], 1);
}

__global__ void dinv_kernel(const int* __restrict__ deg, float* __restrict__ dinv) {
    int i = blockIdx.x * blockDim.x + threadIdx.x;
    if (i < N_NODES) dinv[i] = rsqrtf((float)deg[i] + 1.0f);  // +1 self-loop
}

// 3-kernel scan (multi-block)
__global__ __launch_bounds__(256) void scan1_kernel(const int* __restrict__ deg,
                                                    int* __restrict__ local_scan,
                                                    int* __restrict__ partials) {
    __shared__ int sm[256];
    int b = blockIdx.x, t = threadIdx.x;
    int i = b * 256 + t;
    int v = (i < N_NODES) ? deg[i] : 0;
    sm[t] = v;
    __syncthreads();
    for (int off = 1; off < 256; off <<= 1) {
        int x = (t >= off) ? sm[t - off] : 0;
        __syncthreads();
        sm[t] += x;
        __syncthreads();
    }
    if (i < N_NODES) local_scan[i] = sm[t];
    if (t == 255) partials[b] = sm[255];
}

__global__ __launch_bounds__(256) void scan2_kernel(int* __restrict__ partials) {
    __shared__ int sm[256];
    int t = threadIdx.x;
    sm[t] = (t < SCANB) ? partials[t] : 0;
    __syncthreads();
    for (int off = 1; off < 256; off <<= 1) {
        int x = (t >= off) ? sm[t - off] : 0;
        __syncthreads();
        sm[t] += x;
        __syncthreads();
    }
    if (t < SCANB) partials[t] = (t == 0) ? 0 : sm[t - 1];  // exclusive
}

__global__ __launch_bounds__(256) void scan3_kernel(const int* __restrict__ deg,
                                                    const int* __restrict__ local_scan,
                                                    const int* __restrict__ partials,
                                                    int* __restrict__ offsets,
                                                    int* __restrict__ cursor) {
    int i = blockIdx.x * 256 + threadIdx.x;
    if (i == 0) offsets[0] = 0;
    if (i < N_NODES) {
        int incl = local_scan[i] + partials[blockIdx.x];
        offsets[i + 1] = incl;
        cursor[i] = incl - deg[i];
    }
}

// packed CSR entry: {src, weight-as-bits} -> one 8B load per edge
__global__ void fill_csr_kernel(const int* __restrict__ src, const int* __restrict__ dst,
                                int* __restrict__ cursor, int2* __restrict__ csr_sw,
                                const float* __restrict__ dinv) {
    int e = blockIdx.x * blockDim.x + threadIdx.x;
    if (e < N_EDGES) {
        int s = src[e], d = dst[e];
        int p = atomicAdd(&cursor[d], 1);
        csr_sw[p] = make_int2(s, __float_as_int(dinv[s] * dinv[d]));
    }
}

// ---------------- split-bf16 MFMA GEMM (fp16 hi/lo output) ----------------
// R4: XCD-affine block decode. Hardware round-robins blockIdx->XCD (id&7), so
// the old (col,row) grid put the 4 col-blocks sharing an A row-band on 4
// DIFFERENT XCDs -> A fetched ~4x into 4 L2s (~400MB, IC-BW-bound). New decode
// b = xcd + 8*(bh*ncolb + c), r = bh*8 + xcd gives all col-blocks of a band
// the same b&7 -> one L2 fetch of the A band, sharers hit in L2.

typedef __attribute__((ext_vector_type(8))) short bf16x8;
typedef __attribute__((ext_vector_type(4))) float floatx4;

#define GLL16(g, l)                                                                   \
    __builtin_amdgcn_global_load_lds((__attribute__((address_space(1))) const void*)(g), \
                                     (__attribute__((address_space(3))) void*)(l), 16, 0, 0)

__global__ __launch_bounds__(256) void gemm_split_bt(const unsigned short* __restrict__ A2,
                                                     const unsigned short* __restrict__ B2T,
                                                     __half* __restrict__ Chi,
                                                     __half* __restrict__ Clo, int N,
                                                     int cshift) {
    // XCD-affine decode (cshift = log2(ncol_blocks): 2 for N=512, 1 for N=256)
    const int b = blockIdx.x;
    const int xcd = b & 7;
    const int q = b >> 3;
    const int cb = q & ((1 << cshift) - 1);
    const int bh = q >> cshift;
    const int r = bh * 8 + xcd;
    if (r >= NBANDS) return;
    const int row0 = r * 128;
    const int col0 = cb * 128;

    // [buf][hi/lo] 128x32 chunks, double-buffered: 64 KiB total
    __shared__ unsigned short As[2][2][128 * 32];
    __shared__ unsigned short Bs[2][2][128 * 32];

    const int t = threadIdx.x;
    const int lane = t & 63;
    const int quad = lane >> 4;
    const int l15 = lane & 15;
    const int w = t >> 6;
    const int wm = w & 1, wn = w >> 1;

    floatx4 acc[4][4];
#pragma unroll
    for (int i = 0; i < 4; i++)
#pragma unroll
        for (int j = 0; j < 4; j++) acc[i][j] = (floatx4){0.f, 0.f, 0.f, 0.f};

    // coalesced staging with XOR-swizzled k-chunk
    const int sr = t >> 2;
    const int sk = ((t & 3) ^ ((t >> 3) & 3)) * 8;
    const unsigned short* Arow0 = A2 + (size_t)(row0 + sr) * KPHYS + sk;
    const unsigned short* Arow1 = Arow0 + (size_t)64 * KPHYS;
    const unsigned short* Brow0 = B2T + (size_t)(col0 + sr) * KB + sk;
    const unsigned short* Brow1 = Brow0 + (size_t)64 * KB;

    // fragment-read swizzle: chunk column = quad ^ ((l15>>1)&3)
    const int fcol = (quad ^ ((l15 >> 1) & 3)) * 8;

#define STAGE(buf, k32)                                            \
    do {                                                           \
        GLL16(Arow0 + (k32), As[buf][0] + t * 8);                  \
        GLL16(Arow1 + (k32), As[buf][0] + 2048 + t * 8);           \
        GLL16(Arow0 + 512 + (k32), As[buf][1] + t * 8);            \
        GLL16(Arow1 + 512 + (k32), As[buf][1] + 2048 + t * 8);     \
        GLL16(Brow0 + (k32), Bs[buf][0] + t * 8);                  \
        GLL16(Brow1 + (k32), Bs[buf][0] + 2048 + t * 8);           \
        GLL16(Brow0 + 512 + (k32), Bs[buf][1] + t * 8);            \
        GLL16(Brow1 + 512 + (k32), Bs[buf][1] + 2048 + t * 8);     \
    } while (0)

    // prologue: stage chunk 0 into buffer 0
    STAGE(0, 0);

    for (int it = 0; it < NOUTER; it++) {
        const int cur = it & 1;
        __syncthreads();  // drains prefetch into cur; all reads of cur^1 done
        if (it + 1 < NOUTER) STAGE(cur ^ 1, (it + 1) * 32);

        bf16x8 afh[4], afl[4], bfh[4], bfl[4];
#pragma unroll
        for (int mt = 0; mt < 4; mt++) {
            const int ro = (wm * 64 + mt * 16 + l15) * 32 + fcol;
            afh[mt] = *(const bf16x8*)(As[cur][0] + ro);
            afl[mt] = *(const bf16x8*)(As[cur][1] + ro);
        }
#pragma unroll
        for (int nt = 0; nt < 4; nt++) {
            const int ro = (wn * 64 + nt * 16 + l15) * 32 + fcol;
            bfh[nt] = *(const bf16x8*)(Bs[cur][0] + ro);
            bfl[nt] = *(const bf16x8*)(Bs[cur][1] + ro);
        }
        // pass 1: hi*hi
#pragma unroll
        for (int mt = 0; mt < 4; mt++)
#pragma unroll
            for (int nt = 0; nt < 4; nt++)
                acc[mt][nt] = __builtin_amdgcn_mfma_f32_16x16x32_bf16(afh[mt], bfh[nt], acc[mt][nt], 0, 0, 0);
        // pass 2: lo*hi
#pragma unroll
        for (int mt = 0; mt < 4; mt++)
#pragma unroll
            for (int nt = 0; nt < 4; nt++)
                acc[mt][nt] = __builtin_amdgcn_mfma_f32_16x16x32_bf16(afl[mt], bfh[nt], acc[mt][nt], 0, 0, 0);
        // pass 3: hi*lo
#pragma unroll
        for (int mt = 0; mt < 4; mt++)
#pragma unroll
            for (int nt = 0; nt < 4; nt++)
                acc[mt][nt] = __builtin_amdgcn_mfma_f32_16x16x32_bf16(afh[mt], bfl[nt], acc[mt][nt], 0, 0, 0);
    }
#undef STAGE

#pragma unroll
    for (int mt = 0; mt < 4; mt++) {
#pragma unroll
        for (int rr = 0; rr < 4; rr++) {
            int row = row0 + wm * 64 + mt * 16 + quad * 4 + rr;
            __half* Cph = Chi + (size_t)row * N + col0 + wn * 64 + l15;
            __half* Cpl = Clo + (size_t)row * N + col0 + wn * 64 + l15;
#pragma unroll
            for (int nt = 0; nt < 4; nt++) {
                float a = acc[mt][nt][rr];
                __half hi = __float2half(a);
                __half lo = __float2half(a - __half2float(hi));
                Cph[nt * 16] = hi;
                Cpl[nt * 16] = lo;
            }
        }
    }
}

// ---------------- weight split (W [K x N] fp32 -> B2T [N x KB] bf16) ----------------

__global__ void wsplit_kernel(const float* __restrict__ W, unsigned short* __restrict__ B2T, int N) {
    int idx = blockIdx.x * blockDim.x + threadIdx.x;
    if (idx >= 512 * N) return;
    int k = idx / N, n = idx % N;
    float v = W[(size_t)k * N + n];
    unsigned short hi = bf16_rn(v);
    unsigned short lo = bf16_rn(v - bf16_f32(hi));
    unsigned short* row = B2T + (size_t)n * KB;
    row[k] = hi;
    row[512 + k] = lo;
}

// ---------------- x split (fp32 [N_NODES x 512] -> A2 [MPAD x KPHYS]) ----------------

__global__ __launch_bounds__(256) void split_x_kernel(const float* __restrict__ x,
                                                      unsigned short* __restrict__ A2) {
    int m = blockIdx.x;
    int ch = threadIdx.x * 2;
    unsigned short* arow = A2 + (size_t)m * KPHYS;
    float vx = 0.f, vy = 0.f;
    if (m < N_NODES) {
        float2 v = ntload2(x + (size_t)m * 512 + ch);  // x read exactly once
        vx = v.x;
        vy = v.y;
    }
    unsigned short hx = bf16_rn(vx), hy = bf16_rn(vy);
    arow[ch] = hx;
    arow[ch + 1] = hy;
    arow[512 + ch] = bf16_rn(vx - bf16_f32(hx));
    arow[512 + ch + 1] = bf16_rn(vy - bf16_f32(hy));
}

// ---------------- aggregation ----------------

__device__ __forceinline__ float gelu_tanh(float x) {
    float x3 = x * x * x;
    float inner = 0.7978845608028654f * (x + 0.044715f * x3);
    return 0.5f * x * (1.0f + tanhf(inner));
}

// One wave per node: 64 lanes x 8 fp16 ch = 512 ch. 4 nodes per 256-thread block.
// At the structural floor: FETCH ~430MB = 8-XCD x 51MB duplication (random
// graph), IC-path ~3.9 TB/s. R3's deeper unroll traded ILP for occupancy, net
// zero -> keep the 8-deep form (same dur, fewer index stalls).
__global__ __launch_bounds__(256) void aggregate_split_kernel(
    const __half* __restrict__ Chi, const __half* __restrict__ Clo,
    const int* __restrict__ offsets, const int2* __restrict__ csr_sw,
    const float* __restrict__ dinv,
    const float* __restrict__ bias, unsigned short* __restrict__ A2) {
    int t = threadIdx.x;
    int node = __builtin_amdgcn_readfirstlane(blockIdx.x * 4 + (t >> 6));
    int ch = (t & 63) * 8;
    unsigned short* arow = A2 + (size_t)node * KPHYS;
    if (node >= N_NODES) {  // zero pad rows (16B per store)
        *(uint4*)(arow + ch) = make_uint4(0, 0, 0, 0);
        *(uint4*)(arow + 512 + ch) = make_uint4(0, 0, 0, 0);
        return;
    }
    int p0 = offsets[node], p1 = offsets[node + 1];
    float a[8] = {0.f, 0.f, 0.f, 0.f, 0.f, 0.f, 0.f, 0.f};

    union H8 { float4 f4; __half2 h2[4]; };
    int p = p0;
    int pend8 = p0 + ((p1 - p0) & ~7);
    for (; p < pend8; p += 8) {
        int2 e[8];
#pragma unroll
        for (int j = 0; j < 8; j++) e[j] = csr_sw[p + j];
        H8 v[8];
#pragma unroll
        for (int j = 0; j < 8; j++)
            v[j].f4 = *(const float4*)(Chi + (size_t)e[j].x * 512 + ch);
#pragma unroll
        for (int j = 0; j < 8; j++) {
            float wg = __int_as_float(e[j].y);
#pragma unroll
            for (int q = 0; q < 4; q++) {
                float2 c = __half22float2(v[j].h2[q]);
                a[2 * q] += wg * c.x;
                a[2 * q + 1] += wg * c.y;
            }
        }
    }
    if (p + 4 <= p1) {
        int2 e[4];
#pragma unroll
        for (int j = 0; j < 4; j++) e[j] = csr_sw[p + j];
        H8 v[4];
#pragma unroll
        for (int j = 0; j < 4; j++)
            v[j].f4 = *(const float4*)(Chi + (size_t)e[j].x * 512 + ch);
#pragma unroll
        for (int j = 0; j < 4; j++) {
            float wg = __int_as_float(e[j].y);
#pragma unroll
            for (int q = 0; q < 4; q++) {
                float2 c = __half22float2(v[j].h2[q]);
                a[2 * q] += wg * c.x;
                a[2 * q + 1] += wg * c.y;
            }
        }
        p += 4;
    }
    for (; p < p1; p++) {
        int2 e = csr_sw[p];
        float wg = __int_as_float(e.y);
        H8 v;
        v.f4 = *(const float4*)(Chi + (size_t)e.x * 512 + ch);
#pragma unroll
        for (int q = 0; q < 4; q++) {
            float2 c = __half22float2(v.h2[q]);
            a[2 * q] += wg * c.x;
            a[2 * q + 1] += wg * c.y;
        }
    }

    float di = dinv[node];
    float wself = di * di;
    H8 vh, vl;
    vh.f4 = *(const float4*)(Chi + (size_t)node * 512 + ch);
    vl.f4 = *(const float4*)(Clo + (size_t)node * 512 + ch);
    float4 bv0 = *(const float4*)(bias + ch);
    float4 bv1 = *(const float4*)(bias + ch + 4);
    float s[8], b[8] = {bv0.x, bv0.y, bv0.z, bv0.w, bv1.x, bv1.y, bv1.z, bv1.w};
#pragma unroll
    for (int j = 0; j < 4; j++) {
        float2 ch2 = __half22float2(vh.h2[j]);
        float2 cl2 = __half22float2(vl.h2[j]);
        s[2 * j] = ch2.x + cl2.x;
        s[2 * j + 1] = ch2.y + cl2.y;
    }

    unsigned short hi[8], lo[8];
#pragma unroll
    for (int j = 0; j < 8; j++) {
        float v = gelu_tanh(a[j] + wself * s[j] + b[j]);
        hi[j] = bf16_rn(v);
        lo[j] = bf16_rn(v - bf16_f32(hi[j]));
    }
    *(ushort4*)(arow + ch) = make_ushort4(hi[0], hi[1], hi[2], hi[3]);
    *(ushort4*)(arow + ch + 4) = make_ushort4(hi[4], hi[5], hi[6], hi[7]);
    *(ushort4*)(arow + 512 + ch) = make_ushort4(lo[0], lo[1], lo[2], lo[3]);
    *(ushort4*)(arow + 512 + ch + 4) = make_ushort4(lo[4], lo[5], lo[6], lo[7]);
}

// Final agg: 256 ch, one wave per node (64 lanes x 4 fp16 ch), 4 nodes/block.
__global__ __launch_bounds__(256) void aggregate_final_kernel(
    const __half* __restrict__ Chi, const __half* __restrict__ Clo,
    const int* __restrict__ offsets, const int2* __restrict__ csr_sw,
    const float* __restrict__ dinv,
    const float* __restrict__ bias, float* __restrict__ out) {
    int t = threadIdx.x;
    int node = __builtin_amdgcn_readfirstlane(blockIdx.x * 4 + (t >> 6));
    if (node >= N_NODES) return;
    int ch = (t & 63) * 4;
    int p0 = offsets[node], p1 = offsets[node + 1];
    float ax = 0.f, ay = 0.f, az = 0.f, aw = 0.f;

    union H4 { float2 f2; __half2 h2[2]; };
    int p = p0;
    int pend8 = p0 + ((p1 - p0) & ~7);
    for (; p < pend8; p += 8) {
        int2 e[8];
#pragma unroll
        for (int j = 0; j < 8; j++) e[j] = csr_sw[p + j];
        H4 v[8];
#pragma unroll
        for (int j = 0; j < 8; j++)
            v[j].f2 = *(const float2*)(Chi + (size_t)e[j].x * 256 + ch);
#pragma unroll
        for (int j = 0; j < 8; j++) {
            float wg = __int_as_float(e[j].y);
            float2 c0 = __half22float2(v[j].h2[0]), c1 = __half22float2(v[j].h2[1]);
            ax += wg * c0.x; ay += wg * c0.y; az += wg * c1.x; aw += wg * c1.y;
        }
    }
    for (; p < p1; p++) {
        int2 e = csr_sw[p];
        float wg = __int_as_float(e.y);
        H4 v;
        v.f2 = *(const float2*)(Chi + (size_t)e.x * 256 + ch);
        float2 c0 = __half22float2(v.h2[0]), c1 = __half22float2(v.h2[1]);
        ax += wg * c0.x; ay += wg * c0.y; az += wg * c1.x; aw += wg * c1.y;
    }

    float di = dinv[node];
    float wself = di * di;
    H4 vh, vl;
    vh.f2 = *(const float2*)(Chi + (size_t)node * 256 + ch);
    vl.f2 = *(const float2*)(Clo + (size_t)node * 256 + ch);
    float2 h0 = __half22float2(vh.h2[0]), h1 = __half22float2(vh.h2[1]);
    float2 l0 = __half22float2(vl.h2[0]), l1 = __half22float2(vl.h2[1]);
    float4 bv = *(const float4*)(bias + ch);
    float4 o = make_float4(ax + wself * (h0.x + l0.x) + bv.x,
                           ay + wself * (h0.y + l0.y) + bv.y,
                           az + wself * (h1.x + l1.x) + bv.z,
                           aw + wself * (h1.y + l1.y) + bv.w);
    *(float4*)(out + (size_t)node * 256 + ch) = o;
}

// ---------------- launch ----------------

static inline char* align16(char* p) { return (char*)(((size_t)p + 15) & ~(size_t)15); }

extern "C" void kernel_launch(void* const* d_in, const int* in_sizes, int n_in,
                              void* d_out, int out_size, void* d_ws, size_t ws_size,
                              hipStream_t stream) {
    const float* x  = (const float*)d_in[0];
    const int* eidx = (const int*)d_in[1];
    const float* W1 = (const float*)d_in[2];
    const float* b1 = (const float*)d_in[3];
    const float* W2 = (const float*)d_in[4];
    const float* b2 = (const float*)d_in[5];
    const float* W3 = (const float*)d_in[6];
    const float* b3 = (const float*)d_in[7];
    float* out = (float*)d_out;

    const int* src = eidx;
    const int* dst = eidx + N_EDGES;

    char* ws = (char*)d_ws;
    unsigned short* A2 = (unsigned short*)ws;  ws += (size_t)MPAD * KPHYS * 2;   // 102.5 MB
    __half* Chi = (__half*)ws;                 ws += (size_t)MPAD * 512 * 2;      // 51.2 MB
    __half* Clo = (__half*)ws;                 ws += (size_t)MPAD * 512 * 2;      // 51.2 MB
    unsigned short* B2T1 = (unsigned short*)ws; ws += (size_t)512 * KB * 2;
    unsigned short* B2T2 = (unsigned short*)ws; ws += (size_t)512 * KB * 2;
    unsigned short* B2T3 = (unsigned short*)ws; ws += (size_t)256 * KB * 2;
    int* deg = (int*)ws;        ws = align16(ws + (size_t)N_NODES * 4);
    float* dinv = (float*)ws;   ws = align16(ws + (size_t)N_NODES * 4);
    int* offsets = (int*)ws;    ws = align16(ws + (size_t)(N_NODES + 1) * 4);
    int* cursor = (int*)ws;     ws = align16(ws + (size_t)N_NODES * 4);
    int2* csr_sw = (int2*)ws;   ws = align16(ws + (size_t)N_EDGES * 8);
    int* local_scan = (int*)ws; ws = align16(ws + (size_t)N_NODES * 4);
    int* partials = (int*)ws;   ws = align16(ws + (size_t)SCANB * 4);

    // ---- CSR build ----
    zero_int_kernel<<<(N_NODES + 255) / 256, 256, 0, stream>>>(deg, N_NODES);
    count_deg_kernel<<<(N_EDGES + 255) / 256, 256, 0, stream>>>(dst, deg);
    dinv_kernel<<<(N_NODES + 255) / 256, 256, 0, stream>>>(deg, dinv);
    scan1_kernel<<<SCANB, 256, 0, stream>>>(deg, local_scan, partials);
    scan2_kernel<<<1, 256, 0, stream>>>(partials);
    scan3_kernel<<<SCANB, 256, 0, stream>>>(deg, local_scan, partials, offsets, cursor);
    fill_csr_kernel<<<(N_EDGES + 255) / 256, 256, 0, stream>>>(src, dst, cursor, csr_sw, dinv);

    // ---- weight + input splits ----
    wsplit_kernel<<<(512 * 512 + 255) / 256, 256, 0, stream>>>(W1, B2T1, 512);
    wsplit_kernel<<<(512 * 512 + 255) / 256, 256, 0, stream>>>(W2, B2T2, 512);
    wsplit_kernel<<<(512 * 256 + 255) / 256, 256, 0, stream>>>(W3, B2T3, 256);
    split_x_kernel<<<MPAD, 256, 0, stream>>>(x, A2);

    // XCD-affine GEMM grids: blocks = 8 * ceil(NBANDS/8) * ncolb
    const int gemm_grid_512 = 8 * ((NBANDS + 7) / 8) * 4;  // 1568
    const int gemm_grid_256 = 8 * ((NBANDS + 7) / 8) * 2;  // 784

    // ---- layer 1 ----
    {
        gemm_split_bt<<<gemm_grid_512, 256, 0, stream>>>(A2, B2T1, Chi, Clo, 512, 2);
        aggregate_split_kernel<<<MPAD / 4, 256, 0, stream>>>(Chi, Clo, offsets, csr_sw, dinv, b1, A2);
    }
    // ---- layer 2 ----
    {
        gemm_split_bt<<<gemm_grid_512, 256, 0, stream>>>(A2, B2T2, Chi, Clo, 512, 2);
        aggregate_split_kernel<<<MPAD / 4, 256, 0, stream>>>(Chi, Clo, offsets, csr_sw, dinv, b2, A2);
    }
    // ---- layer 3 ----
    {
        gemm_split_bt<<<gemm_grid_256, 256, 0, stream>>>(A2, B2T3, Chi, Clo, 256, 1);
        aggregate_final_kernel<<<MPAD / 4, 256, 0, stream>>>(Chi, Clo, offsets, csr_sw, dinv, b3, out);
    }
}